// Round 9
// baseline (680.260 us; speedup 1.0000x reference)
//
#include <hip/hip_runtime.h>
#include <stdint.h>

typedef __attribute__((ext_vector_type(8))) short short8;
typedef __attribute__((ext_vector_type(4))) float f32x4;
typedef unsigned short u16;
typedef unsigned int u32;
typedef unsigned long long u64;

// ---------------- workspace layout (bytes) ----------------
#define WS_TOK   0ull           // tokens bf16 [32768][256]            16 MB
#define WS_XT    16777216ull    // x_t -> xm_tc -> r1 fp32 [T][C]      32 MB
#define WS_XMCT  50331648ull    // xm fp32 [C][T]                      32 MB
#define WS_GATES 83886080ull    // gw fp32 [T][2] | tpos u32 [T][2]
#define WS_H     84934656ull    // perm/meta/sel region (16 MB)
#define WS_P1    135266304ull   // padded bf16 [34^3][256]             19.2MB
#define WS_P2    155389952ull
#define WS_Y     175513600ull   // conv y bf16 [T][256] / eo bf16 [66560][256]
#define WS_R2    209068032ull   // r2 bf16 [T][256]
#define WS_WRB   225845248ull   // packed rb conv w bf16 [4][27][256][256]
#define WS_W1P   240001024ull
#define WS_W2P   241049600ull
#define WS_C8P   242098176ull
#define WS_PART  242229248ull   // bn partials [2][512][256] fp32 (1MB)
#define WS_SF    243277824ull   // bn scale/shift [2][256]
#define WS_AUXP  243279872ull   // aux partials [128][16]

#define WS_PERM  (WS_H + 0x00000ull)
#define WS_TBL   (WS_H + 0x60000ull)
#define WS_META  (WS_H + 0x70000ull)
#define WS_BCNT  (WS_H + 0x80000ull)
#define WS_BOFF  (WS_H + 0x90000ull)
#define WS_SEL   (WS_H + 0x100000ull)

__device__ __forceinline__ u16 f2bf(float f) {
  u32 x = __float_as_uint(f);
  u32 r = x + 0x7fffu + ((x >> 16) & 1u);
  return (u16)(r >> 16);
}
__device__ __forceinline__ float bf2f(u32 u) { return __uint_as_float(u << 16); }

// ---------------- transpose x [C][T] -> x_t fp32 + tokens bf16 [T][C] ----------------
__global__ void trans_in_k(const float* __restrict__ x, float* __restrict__ xt,
                           u16* __restrict__ tok) {
  __shared__ float ld[64][65];
  int tt = blockIdx.x, cc = blockIdx.y, tid = threadIdx.x;
#pragma unroll
  for (int k = 0; k < 16; ++k) {
    int idx = tid + k * 256;
    int cl = idx >> 6, j = idx & 63;
    ld[cl][j] = x[(size_t)(cc * 64 + cl) * 32768 + tt * 64 + j];
  }
  __syncthreads();
#pragma unroll
  for (int k = 0; k < 16; ++k) {
    int idx = tid + k * 256;
    int tl = idx >> 6, cl = idx & 63;
    float v = ld[cl][tl];
    size_t o = (size_t)(tt * 64 + tl) * 256 + cc * 64 + cl;
    xt[o] = v;
    tok[o] = f2bf(v);
  }
}

// ---------------- pack resblock conv weights ----------------
__global__ void pack_rb_k(const float* __restrict__ w0, const float* __restrict__ w1,
                          const float* __restrict__ w2, const float* __restrict__ w3,
                          u16* __restrict__ out) {
  __shared__ float ld[6912];
  int conv = blockIdx.x >> 8, blk = blockIdx.x & 255, tid = threadIdx.x;
  const float* src = conv == 0 ? w0 : conv == 1 ? w1 : conv == 2 ? w2 : w3;
  size_t base = (size_t)blk * 256 * 27;
#pragma unroll
  for (int k = 0; k < 27; ++k) ld[tid + k * 256] = src[base + tid + k * 256];
  __syncthreads();
  u16* dst = out + (size_t)conv * 27 * 65536;
  int n = blk * 256 + tid;
#pragma unroll
  for (int tap = 0; tap < 27; ++tap)
    dst[(size_t)tap * 65536 + n] = f2bf(ld[tid * 27 + tap]);
}

// ---------------- transpose-pack w1/w2 256x256 matrices to [N][K] bf16 ----------------
__global__ void pack_tr_k(const float* __restrict__ w1, const float* __restrict__ w2,
                          u16* __restrict__ w1p, u16* __restrict__ w2p) {
  __shared__ float ld[64][65];
  int m = blockIdx.y, tile = blockIdx.x, tid = threadIdx.x;
  const float* src = (m < 8) ? (w1 + (size_t)m * 65536) : (w2 + (size_t)(m - 8) * 65536);
  u16* dst = (m < 8) ? (w1p + (size_t)m * 65536) : (w2p + (size_t)(m - 8) * 65536);
  int r0 = (tile >> 2) * 64, c0 = (tile & 3) * 64;
#pragma unroll
  for (int k = 0; k < 16; ++k) {
    int idx = tid + k * 256;
    int rr = idx >> 6, cc = idx & 63;
    ld[rr][cc] = src[(size_t)(r0 + rr) * 256 + c0 + cc];
  }
  __syncthreads();
#pragma unroll
  for (int k = 0; k < 16; ++k) {
    int idx = tid + k * 256;
    int cc = idx >> 6, rr = idx & 63;
    dst[(size_t)(c0 + cc) * 256 + r0 + rr] = f2bf(ld[rr][cc]);
  }
}

__global__ void cvt_k(const float* __restrict__ in, u16* __restrict__ out, int n) {
  int i = blockIdx.x * 256 + threadIdx.x;
  if (i < n) out[i] = f2bf(in[i]);
}

// ---------------- zero halo rows of both padded buffers ----------------
__global__ void halo_k(u16* __restrict__ P1, u16* __restrict__ P2) {
  int gid = blockIdx.x * 256 + threadIdx.x;
  int r = gid >> 5, o = (gid & 31) << 3;
  if (r >= 39304) return;
  int d = r / 1156, rem = r - d * 1156, h = rem / 34, w = rem - h * 34;
  if (d >= 1 && d <= 32 && h >= 1 && h <= 32 && w >= 1 && w <= 32) return;
  uint4 z = {0u, 0u, 0u, 0u};
  *(uint4*)(P1 + (size_t)r * 256 + o) = z;
  *(uint4*)(P2 + (size_t)r * 256 + o) = z;
}

// ---------------- gating: reads x [C][T] (coalesced); softmax + top2 + aux ----------
__global__ void gate_k(const float* __restrict__ x, const float* __restrict__ wg,
                       float* __restrict__ gw, u32* __restrict__ sel,
                       u32* __restrict__ blk_cnt, float* __restrict__ auxp) {
  __shared__ float wgs[2048];
  __shared__ float ax[4][16];
  __shared__ u32 bc[4][8];
  int tid = threadIdx.x;
#pragma unroll
  for (int k = 0; k < 8; ++k) wgs[tid + k * 256] = wg[tid + k * 256];
  __syncthreads();
  int t = blockIdx.x * 256 + tid;
  int lane = tid & 63, wv = tid >> 6;
  float l[8] = {0, 0, 0, 0, 0, 0, 0, 0};
#pragma unroll 4
  for (int c = 0; c < 256; ++c) {
    float xv = x[(size_t)c * 32768 + t];
#pragma unroll
    for (int e = 0; e < 8; ++e) l[e] += xv * wgs[c * 8 + e];
  }
  float mx = l[0];
#pragma unroll
  for (int e = 1; e < 8; ++e) mx = fmaxf(mx, l[e]);
  float p[8], sum = 0.f;
#pragma unroll
  for (int e = 0; e < 8; ++e) { p[e] = __expf(l[e] - mx); sum += p[e]; }
  float inv = 1.0f / sum;
#pragma unroll
  for (int e = 0; e < 8; ++e) p[e] *= inv;
  int i0 = 0; float v0 = p[0];
#pragma unroll
  for (int e = 1; e < 8; ++e) if (p[e] > v0) { v0 = p[e]; i0 = e; }
  int i1 = -1; float v1 = -1.0f;
#pragma unroll
  for (int e = 0; e < 8; ++e) if (e != i0 && p[e] > v1) { v1 = p[e]; i1 = e; }
  float wsum = v0 + v1;
  gw[t * 2] = v0 / wsum;
  gw[t * 2 + 1] = v1 / wsum;
  sel[t] = (u32)i0 | ((u32)i1 << 4);
  u64 mm[8];
#pragma unroll
  for (int e = 0; e < 8; ++e) mm[e] = __ballot(i0 == e || i1 == e);
  if (lane == 0) {
#pragma unroll
    for (int e = 0; e < 8; ++e) bc[wv][e] = (u32)__popcll(mm[e]);
  }
#pragma unroll
  for (int e = 0; e < 8; ++e) {
    float ps = p[e];
    float cn = (e == i0 || e == i1) ? 1.0f : 0.0f;
    for (int o = 32; o; o >>= 1) { ps += __shfl_down(ps, o); cn += __shfl_down(cn, o); }
    if (lane == 0) { ax[wv][e] = ps; ax[wv][8 + e] = cn; }
  }
  __syncthreads();
  if (tid < 16)
    auxp[blockIdx.x * 16 + tid] = ax[0][tid] + ax[1][tid] + ax[2][tid] + ax[3][tid];
  if (tid < 8)
    blk_cnt[blockIdx.x * 8 + tid] = bc[0][tid] + bc[1][tid] + bc[2][tid] + bc[3][tid];
}

__global__ void aux_k(const float* __restrict__ auxp, float* __restrict__ out) {
  __shared__ float s[16];
  int i = threadIdx.x;
  if (i < 16) {
    float a = 0;
    for (int b = 0; b < 128; ++b) a += auxp[b * 16 + i];
    s[i] = a;
  }
  __syncthreads();
  if (i == 0) {
    float r = 0;
    for (int e = 0; e < 8; ++e)
      r += (s[8 + e] * (1.0f / 32768.0f)) * (s[e] * (1.0f / 32768.0f));
    out[0] = r * 8.0f;
  }
}

// ---------------- scan: block counts -> absolute offsets, chunk table, perm pads ----
__global__ void scan_k(const u32* __restrict__ blk_cnt, u32* __restrict__ blkoff,
                       u32* __restrict__ tbl, u32* __restrict__ meta,
                       u32* __restrict__ perm) {
  __shared__ u32 tot[8], base[8], nck[8], cbase[8];
  int tid = threadIdx.x;
  if (tid < 8) {
    u32 run = 0;
    for (int b = 0; b < 128; ++b) {
      blkoff[b * 8 + tid] = run;
      run += blk_cnt[b * 8 + tid];
    }
    tot[tid] = run;
  }
  __syncthreads();
  if (tid == 0) {
    u32 acc = 0, c = 0;
    for (int e = 0; e < 8; ++e) {
      base[e] = acc;
      u32 nc = (tot[e] + 127) >> 7;
      nck[e] = nc;
      cbase[e] = c;
      acc += nc << 7;
      c += nc;
    }
    meta[0] = c;
  }
  __syncthreads();
  for (int i = tid; i < 1024; i += 256) blkoff[i] += base[i & 7];
  if (tid < 8) {
    for (u32 k = 0; k < nck[tid]; ++k)
      tbl[cbase[tid] + k] = ((base[tid] + (k << 7)) << 4) | (u32)tid;
    for (u32 sl = base[tid] + tot[tid]; sl < base[tid] + (nck[tid] << 7); ++sl)
      perm[sl] = 0;
  }
}

// ---------------- scatter: deterministic positions via ballot ranks ----------------
__global__ void scatter_k(const u32* __restrict__ sel, const u32* __restrict__ blkoff,
                          u32* __restrict__ perm, u32* __restrict__ tpos) {
  __shared__ u32 wcnt[4][8];
  int tid = threadIdx.x, b = blockIdx.x;
  int lane = tid & 63, wv = tid >> 6;
  int t = b * 256 + tid;
  u32 s = sel[t];
  int i0 = s & 15, i1 = (s >> 4) & 15;
  u64 mm[8];
#pragma unroll
  for (int e = 0; e < 8; ++e) mm[e] = __ballot(i0 == e || i1 == e);
  if (lane == 0) {
#pragma unroll
    for (int e = 0; e < 8; ++e) wcnt[wv][e] = (u32)__popcll(mm[e]);
  }
  __syncthreads();
  u64 lt = (1ull << lane) - 1ull;
#pragma unroll
  for (int e = 0; e < 8; ++e) {
    bool is0 = (i0 == e), is1 = (i1 == e);
    if (is0 || is1) {
      u32 woff = 0;
#pragma unroll
      for (int w = 0; w < 4; ++w)
        if (w < wv) woff += wcnt[w][e];
      u32 pos = blkoff[b * 8 + e] + woff + (u32)__popcll(mm[e] & lt);
      perm[pos] = (u32)t;
      tpos[t * 2 + (is0 ? 0 : 1)] = pos;
    }
  }
}

// ---------------- sparse MoE GEMM: w-dbuf + Hs aliased onto tok region -------------
// LDS: [0,64K) tok -> Hs | [64K,96K) wbuf0 | [96K,128K) wbuf1. 1 sync per kc step.
__global__ __launch_bounds__(512, 2) void moe_gemm_k(
    const u16* __restrict__ tok, const u32* __restrict__ perm,
    const u32* __restrict__ tbl, const u32* __restrict__ meta,
    const u16* __restrict__ w1p, const u16* __restrict__ w2p,
    const float* __restrict__ b1, const float* __restrict__ b2,
    u16* __restrict__ eo) {
  __shared__ __attribute__((aligned(16))) unsigned char smem[131072];
  const int bid = blockIdx.x;
  if ((u32)bid >= meta[0]) return;
  const u32 ent = tbl[bid];
  const int e = (int)(ent & 15u);
  const int slot0 = (int)(ent >> 4);
  const int tid = threadIdx.x;
  const int lane = tid & 63;
  const int wv = tid >> 6;
  const int wr = (wv >> 2) * 64;
  const int wc = (wv & 3) * 64;
  const int fq = lane >> 4, fr = lane & 15;
  const u16* w1e = w1p + e * 65536;
  const u16* w2e = w2p + e * 65536;

  // weight staging offsets (4 chunks/thread)
  int woff[4];
#pragma unroll
  for (int it = 0; it < 4; ++it) {
    int s = tid + it * 512;
    int r = s >> 3;
    woff[it] = r * 256 + (((s & 7) ^ (r & 7)) << 3);
  }

  // prologue: gathered tok rows [128][256] + w1 kc0 -> wbuf0
#pragma unroll
  for (int it = 0; it < 8; ++it) {
    int s = tid + it * 512;
    int r = s >> 5, seg = s & 31;
    int cole = ((seg >> 3) << 6) + (((seg & 7) ^ (r & 7)) << 3);
    u32 rowtok = perm[slot0 + r];
    __builtin_amdgcn_global_load_lds(
        (const __attribute__((address_space(1))) u32*)(tok + (size_t)rowtok * 256 + cole),
        (__attribute__((address_space(3))) u32*)(smem + s * 16), 16, 0, 0);
  }
#pragma unroll
  for (int it = 0; it < 4; ++it)
    __builtin_amdgcn_global_load_lds(
        (const __attribute__((address_space(1))) u32*)(w1e + woff[it]),
        (__attribute__((address_space(3))) u32*)(smem + 65536 + (tid + it * 512) * 16),
        16, 0, 0);
  __syncthreads();

  // ---- GEMM1 (swapped): acc1[mc][nt] = w1-rows x tok-rows -> h^T frags ----
  f32x4 acc1[4][4];
#pragma unroll
  for (int mc = 0; mc < 4; ++mc)
#pragma unroll
    for (int nt = 0; nt < 4; ++nt) acc1[mc][nt] = (f32x4){0.f, 0.f, 0.f, 0.f};

#pragma unroll 1
  for (int kc = 0; kc < 4; ++kc) {
    // stage next weights: w1(kc+1), or w2(0) at kc==3 (prefetch GEMM2)
    const u16* nw = (kc < 3) ? (w1e + (kc + 1) * 64) : w2e;
    unsigned char* nb = smem + 65536 + (((kc + 1) & 1) * 32768);
#pragma unroll
    for (int it = 0; it < 4; ++it)
      __builtin_amdgcn_global_load_lds(
          (const __attribute__((address_space(1))) u32*)(nw + woff[it]),
          (__attribute__((address_space(3))) u32*)(nb + (tid + it * 512) * 16),
          16, 0, 0);
    const unsigned char* wb = smem + 65536 + ((kc & 1) * 32768);
#pragma unroll
    for (int khf = 0; khf < 2; ++khf) {
      short8 af1[4], bt[4];
#pragma unroll
      for (int mc = 0; mc < 4; ++mc) {
        int row = wc + mc * 16 + fr;
        int p = (khf * 4 + fq) ^ (row & 7);
        af1[mc] = *(const short8*)(wb + row * 128 + p * 16);
      }
#pragma unroll
      for (int nt = 0; nt < 4; ++nt) {
        int row = wr + nt * 16 + fr;
        int p = (khf * 4 + fq) ^ (row & 7);
        bt[nt] = *(const short8*)(smem + row * 512 + kc * 128 + p * 16);
      }
#pragma unroll
      for (int mc = 0; mc < 4; ++mc)
#pragma unroll
        for (int nt = 0; nt < 4; ++nt)
          acc1[mc][nt] = __builtin_amdgcn_mfma_f32_16x16x32_bf16(af1[mc], bt[nt], acc1[mc][nt], 0, 0, 0);
    }
    __syncthreads();
  }

  // epilogue: h = gelu(acc1 + b1[c]) -> Hs (aliases tok region; all tok reads done)
#pragma unroll
  for (int mc = 0; mc < 4; ++mc) {
    int k0 = wc + mc * 16 + fq * 4;
    float4 bv = *(const float4*)(b1 + e * 256 + k0);
#pragma unroll
    for (int nt = 0; nt < 4; ++nt) {
      int t = wr + nt * 16 + fr;
      u64 pk = 0;
#pragma unroll
      for (int j = 0; j < 4; ++j) {
        float v = acc1[mc][nt][j] + ((const float*)&bv)[j];
        float u = 1.5957691216057308f * (v + 0.044715f * v * v * v);
        float g = v / (1.0f + __expf(-u));
        pk |= (u64)f2bf(g) << (16 * j);
      }
      *(u64*)(smem + t * 512 + ((k0 * 2) ^ ((t & 7) << 4))) = pk;
    }
  }
  __syncthreads();  // Hs visible; wbuf0 already holds w2 kc0

  // ---- GEMM2: acc2[m][n] = h-rows x w2-rows ----
  f32x4 acc2[4][4];
#pragma unroll
  for (int m = 0; m < 4; ++m)
#pragma unroll
    for (int n = 0; n < 4; ++n) acc2[m][n] = (f32x4){0.f, 0.f, 0.f, 0.f};

#pragma unroll 1
  for (int kc = 0; kc < 4; ++kc) {
    if (kc < 3) {
      unsigned char* nb = smem + 65536 + (((kc + 1) & 1) * 32768);
      const u16* nw = w2e + (kc + 1) * 64;
#pragma unroll
      for (int it = 0; it < 4; ++it)
        __builtin_amdgcn_global_load_lds(
            (const __attribute__((address_space(1))) u32*)(nw + woff[it]),
            (__attribute__((address_space(3))) u32*)(nb + (tid + it * 512) * 16),
            16, 0, 0);
    }
    const unsigned char* wb = smem + 65536 + ((kc & 1) * 32768);
#pragma unroll
    for (int khf = 0; khf < 2; ++khf) {
      short8 af[4], bb[4];
#pragma unroll
      for (int m = 0; m < 4; ++m) {
        int row = wr + m * 16 + fr;
        int col = (kc * 128 + (khf * 4 + fq) * 16) ^ ((row & 7) << 4);
        af[m] = *(const short8*)(smem + row * 512 + col);
      }
#pragma unroll
      for (int n = 0; n < 4; ++n) {
        int row = wc + n * 16 + fr;
        int p = (khf * 4 + fq) ^ (row & 7);
        bb[n] = *(const short8*)(wb + row * 128 + p * 16);
      }
#pragma unroll
      for (int m = 0; m < 4; ++m)
#pragma unroll
        for (int n = 0; n < 4; ++n)
          acc2[m][n] = __builtin_amdgcn_mfma_f32_16x16x32_bf16(af[m], bb[n], acc2[m][n], 0, 0, 0);
    }
    __syncthreads();
  }

  float bs2[4];
#pragma unroll
  for (int n = 0; n < 4; ++n) bs2[n] = b2[e * 256 + wc + n * 16 + fr];
#pragma unroll
  for (int m = 0; m < 4; ++m)
#pragma unroll
    for (int j = 0; j < 4; ++j) {
      int rowslot = slot0 + wr + m * 16 + fq * 4 + j;
      u16* er = eo + (size_t)rowslot * 256 + wc;
#pragma unroll
      for (int n = 0; n < 4; ++n) er[n * 16 + fr] = f2bf(acc2[m][n][j] + bs2[n]);
    }
}

// ---------------- combine: xm = x + g0*eo[p0] + g1*eo[p1]; write xt/xmct/pad --------
__global__ void combine_k(float* __restrict__ xt, const u16* __restrict__ eo,
                          const float* __restrict__ gw, const u32* __restrict__ tpos,
                          float* __restrict__ xmct, u16* __restrict__ pad) {
  __shared__ float ld[64][65];
  __shared__ u32 pp[64][2];
  __shared__ float gg[64][2];
  int tt = blockIdx.x, cc = blockIdx.y, tid = threadIdx.x;
  if (tid < 128) {
    int tl = tid >> 1, s = tid & 1;
    int t = tt * 64 + tl;
    pp[tl][s] = tpos[t * 2 + s];
    gg[tl][s] = gw[t * 2 + s];
  }
  __syncthreads();
#pragma unroll
  for (int k = 0; k < 16; ++k) {
    int idx = tid + k * 256;
    int tl = idx >> 6, cl = idx & 63;
    int c = cc * 64 + cl;
    size_t o = (size_t)(tt * 64 + tl) * 256 + c;
    float e0 = bf2f(eo[(size_t)pp[tl][0] * 256 + c]);
    float e1 = bf2f(eo[(size_t)pp[tl][1] * 256 + c]);
    float v = xt[o] + gg[tl][0] * e0 + gg[tl][1] * e1;
    xt[o] = v;
    ld[tl][cl] = v;
    int t = tt * 64 + tl;
    int d = t >> 10, h = (t >> 5) & 31, w = t & 31;
    int prow = (d + 1) * 1156 + (h + 1) * 34 + (w + 1);
    pad[(size_t)prow * 256 + c] = f2bf(v);
  }
  __syncthreads();
#pragma unroll
  for (int k = 0; k < 16; ++k) {
    int idx = tid + k * 256;
    int cl = idx >> 6, tl = idx & 63;
    xmct[(size_t)(cc * 64 + cl) * 32768 + tt * 64 + tl] = ld[tl][cl];
  }
}

// ---------------- conv3x3x3: BM=128 BN=256, 512thr, 3-buffer, counted vmcnt(6) ------
// 8 waves (2M x 4N, wave tile 64x64). LDS: 3 x (A 16KB | B 32KB) = 144KB, 1 blk/CU.
// Per step: issue stage(s+2) -> compute(s%3) -> vmcnt(6) [stage(s+1) done,
// stage(s+2) in flight] -> barrier. ONE barrier per step; never drains to 0.
__global__ __launch_bounds__(512, 1) void conv_k(
    const u16* __restrict__ P, const u16* __restrict__ W,
    const float* __restrict__ bias, u16* __restrict__ y,
    float* __restrict__ part) {
  __shared__ __attribute__((aligned(16))) unsigned char smem[147456];
  const int tid = threadIdx.x;
  const int bx = blockIdx.x;
  const int ttile = (bx & 7) * 32 + (bx >> 3);  // XCD-bijective (256 = 8*32)
  const int lane = tid & 63;
  const int wv = tid >> 6;
  const int wr = (wv >> 2) << 6;   // 0,64
  const int wc = (wv & 3) << 6;    // 0,64,128,192
  const int fq = lane >> 4, fr = lane & 15;
  const int dd = ttile >> 3, h0 = (ttile & 7) << 2;

  int aoff[2];
#pragma unroll
  for (int it = 0; it < 2; ++it) {
    int s = tid + it * 512;
    int r = s >> 3, c = s & 7;
    int base = dd * 1156 + (h0 + (r >> 5)) * 34 + (r & 31);
    aoff[it] = base * 256 + ((c ^ (r & 7)) << 3);
  }
  int boff[4];
#pragma unroll
  for (int it = 0; it < 4; ++it) {
    int s = tid + it * 512;
    int r = s >> 3, c = s & 7;
    boff[it] = r * 256 + ((c ^ (r & 7)) << 3);
  }

  f32x4 acc[4][4];
#pragma unroll
  for (int m = 0; m < 4; ++m)
#pragma unroll
    for (int n = 0; n < 4; ++n) acc[m][n] = (f32x4){0.f, 0.f, 0.f, 0.f};

  auto stage = [&](int s, int buf) {
    int tap = s >> 2, kc = s & 3;
    int aofs = ((tap / 9) * 1156 + ((tap / 3) % 3) * 34 + (tap % 3)) * 256 + kc * 64;
    int bofs = tap * 65536 + kc * 64;
    unsigned char* sb = smem + buf * 49152;
#pragma unroll
    for (int it = 0; it < 2; ++it)
      __builtin_amdgcn_global_load_lds(
          (const __attribute__((address_space(1))) u32*)(P + aofs + aoff[it]),
          (__attribute__((address_space(3))) u32*)(sb + (tid + it * 512) * 16),
          16, 0, 0);
#pragma unroll
    for (int it = 0; it < 4; ++it)
      __builtin_amdgcn_global_load_lds(
          (const __attribute__((address_space(1))) u32*)(W + bofs + boff[it]),
          (__attribute__((address_space(3))) u32*)(sb + 16384 + (tid + it * 512) * 16),
          16, 0, 0);
  };
  auto compute = [&](int buf) {
    const unsigned char* sb = smem + buf * 49152;
#pragma unroll
    for (int khf = 0; khf < 2; ++khf) {
      short8 af[4], bb[4];
#pragma unroll
      for (int m = 0; m < 4; ++m) {
        int row = wr + m * 16 + fr;
        int p = (khf * 4 + fq) ^ (row & 7);
        af[m] = *(const short8*)(sb + row * 128 + p * 16);
      }
#pragma unroll
      for (int n = 0; n < 4; ++n) {
        int row = wc + n * 16 + fr;
        int p = (khf * 4 + fq) ^ (row & 7);
        bb[n] = *(const short8*)(sb + 16384 + row * 128 + p * 16);
      }
#pragma unroll
      for (int m = 0; m < 4; ++m)
#pragma unroll
        for (int n = 0; n < 4; ++n)
          acc[m][n] = __builtin_amdgcn_mfma_f32_16x16x32_bf16(af[m], bb[n], acc[m][n], 0, 0, 0);
    }
  };

  // prologue: steps 0,1 staged; wait step 0 only (step 1's 6 loads in flight)
  stage(0, 0);
  stage(1, 1);
  asm volatile("s_waitcnt vmcnt(6)" ::: "memory");
  __builtin_amdgcn_s_barrier();

#pragma unroll 1
  for (int s = 0; s < 108; ++s) {
    if (s < 106) stage(s + 2, (s + 2) % 3);
    compute(s % 3);
    if (s < 106)
      asm volatile("s_waitcnt vmcnt(6)" ::: "memory");
    else
      asm volatile("s_waitcnt vmcnt(0)" ::: "memory");
    __builtin_amdgcn_s_barrier();
  }

  float bs[4];
#pragma unroll
  for (int n = 0; n < 4; ++n) bs[n] = bias[wc + n * 16 + fr];

  float sn[4] = {0, 0, 0, 0}, qn[4] = {0, 0, 0, 0};
#pragma unroll
  for (int m = 0; m < 4; ++m) {
#pragma unroll
    for (int j = 0; j < 4; ++j) {
      int t = ttile * 128 + wr + m * 16 + fq * 4 + j;
      u16* yr = y + (size_t)t * 256 + wc;
#pragma unroll
      for (int n = 0; n < 4; ++n) {
        float v = acc[m][n][j] + bs[n];
        yr[n * 16 + fr] = f2bf(v);
        sn[n] += v;
        qn[n] += v * v;
      }
    }
  }
#pragma unroll
  for (int n = 0; n < 4; ++n) {
    float s = sn[n], q = qn[n];
    s += __shfl_xor(s, 16); s += __shfl_xor(s, 32);
    q += __shfl_xor(q, 16); q += __shfl_xor(q, 32);
    if (lane < 16) {
      int pi = (ttile * 2 + (wv >> 2)) * 256 + wc + n * 16 + fr;
      part[pi] = s;
      part[131072 + pi] = q;
    }
  }
}

// ---------------- final 1x1 conv (2-phase dbuf, proven): out = acc+bias+xmct --------
__global__ __launch_bounds__(256, 2) void final_k(
    const u16* __restrict__ A, const u16* __restrict__ Bw,
    const float* __restrict__ bias, float* __restrict__ outF,
    const float* __restrict__ xmct) {
  __shared__ __attribute__((aligned(16))) unsigned char smem[65536];
  const int tid = threadIdx.x;
  const int ttile = blockIdx.x;
  const int ctile = blockIdx.y;
  const int lane = tid & 63;
  const int wv = tid >> 6;
  const int wr = (wv >> 1) << 6;
  const int wc = (wv & 1) << 6;
  const int fq = lane >> 4;
  const int fr = lane & 15;

  int aoff[4], boff[4];
#pragma unroll
  for (int it = 0; it < 4; ++it) {
    int s = tid + it * 256;
    int r = s >> 3;
    int lsg = (s & 7) ^ (r & 7);
    aoff[it] = (ttile * 128 + r) * 256 + lsg * 8;
    boff[it] = (ctile * 128 + r) * 256 + lsg * 8;
  }

  f32x4 acc[4][4];
#pragma unroll
  for (int m = 0; m < 4; ++m)
#pragma unroll
    for (int n = 0; n < 4; ++n) acc[m][n] = (f32x4){0.f, 0.f, 0.f, 0.f};

  auto stage = [&](int kc, int buf) {
    const u16* Ak = A + kc * 64;
    const u16* Bk = Bw + kc * 64;
    unsigned char* sb = smem + buf * 32768;
#pragma unroll
    for (int it = 0; it < 4; ++it) {
      __builtin_amdgcn_global_load_lds(
          (const __attribute__((address_space(1))) u32*)(Ak + aoff[it]),
          (__attribute__((address_space(3))) u32*)(sb + (tid + it * 256) * 16),
          16, 0, 0);
      __builtin_amdgcn_global_load_lds(
          (const __attribute__((address_space(1))) u32*)(Bk + boff[it]),
          (__attribute__((address_space(3))) u32*)(sb + 16384 + (tid + it * 256) * 16),
          16, 0, 0);
    }
  };
  auto compute = [&](int buf) {
    const unsigned char* sb = smem + buf * 32768;
#pragma unroll
    for (int khf = 0; khf < 2; ++khf) {
      short8 af[4], bb[4];
#pragma unroll
      for (int m = 0; m < 4; ++m) {
        int row = wr + m * 16 + fr;
        int p = (khf * 4 + fq) ^ (row & 7);
        af[m] = *(const short8*)(sb + row * 128 + p * 16);
      }
#pragma unroll
      for (int n = 0; n < 4; ++n) {
        int row = wc + n * 16 + fr;
        int p = (khf * 4 + fq) ^ (row & 7);
        bb[n] = *(const short8*)(sb + 16384 + row * 128 + p * 16);
      }
#pragma unroll
      for (int m = 0; m < 4; ++m)
#pragma unroll
        for (int n = 0; n < 4; ++n)
          acc[m][n] = __builtin_amdgcn_mfma_f32_16x16x32_bf16(af[m], bb[n], acc[m][n], 0, 0, 0);
    }
  };

  stage(0, 0);
  asm volatile("s_waitcnt vmcnt(0)" ::: "memory");
  __builtin_amdgcn_s_barrier();
  int cur = 0;
#pragma unroll 1
  for (int s = 0; s < 4; ++s) {
    if (s + 1 < 4) stage(s + 1, cur ^ 1);
    compute(cur);
    asm volatile("s_waitcnt vmcnt(0)" ::: "memory");
    __builtin_amdgcn_s_barrier();
    cur ^= 1;
  }

  float bs[4];
#pragma unroll
  for (int n = 0; n < 4; ++n) bs[n] = bias[ctile * 128 + wc + n * 16 + fr];

#pragma unroll
  for (int m = 0; m < 4; ++m) {
    int trow = ttile * 128 + wr + m * 16 + fq * 4;
#pragma unroll
    for (int n = 0; n < 4; ++n) {
      int oc = ctile * 128 + wc + n * 16 + fr;
      size_t o = (size_t)oc * 32768 + trow;
      float4 xv = *(const float4*)(xmct + o);
      float4 w;
      w.x = acc[m][n][0] + bs[n] + xv.x;
      w.y = acc[m][n][1] + bs[n] + xv.y;
      w.z = acc[m][n][2] + bs[n] + xv.z;
      w.w = acc[m][n][3] + bs[n] + xv.w;
      *(float4*)(outF + o) = w;
    }
  }
}

// ---------------- BN stats reduce: 16 blocks x 16 channels ----------------
__global__ void stats2_k(const float* __restrict__ part, const float* __restrict__ g,
                         const float* __restrict__ be, float* __restrict__ sf) {
  __shared__ float sred[16][16], qred[16][16];
  int tid = threadIdx.x;
  int cl = tid & 15, ch = tid >> 4;
  int c = blockIdx.x * 16 + cl;
  float s = 0, q = 0;
  for (int b = ch * 32; b < ch * 32 + 32; ++b) {
    s += part[b * 256 + c];
    q += part[131072 + b * 256 + c];
  }
  sred[ch][cl] = s;
  qred[ch][cl] = q;
  __syncthreads();
  if (ch == 0) {
    s = 0; q = 0;
#pragma unroll
    for (int k = 0; k < 16; ++k) { s += sred[k][cl]; q += qred[k][cl]; }
    float mean = s * (1.0f / 32768.0f);
    float var = q * (1.0f / 32768.0f) - mean * mean;
    float a = g[c] * rsqrtf(var + 1e-5f);
    sf[c] = a;
    sf[256 + c] = be[c] - mean * a;
  }
}

// ---------------- BN apply (+leaky, +skip); y is bf16 ----------------
template <int V>
__global__ void bn_k(const u16* __restrict__ y, const float* __restrict__ sf,
                     const float* __restrict__ skip, u16* __restrict__ pad,
                     float* __restrict__ f32o, u16* __restrict__ bfo) {
  int gid = blockIdx.x * 256 + threadIdx.x;
  int t = gid >> 5, c0 = (gid & 31) << 3;
  size_t base = (size_t)t * 256 + c0;
  float v[8];
  uint4 yv = *(const uint4*)(y + base);
  v[0] = bf2f(yv.x & 0xffffu); v[1] = bf2f(yv.x >> 16);
  v[2] = bf2f(yv.y & 0xffffu); v[3] = bf2f(yv.y >> 16);
  v[4] = bf2f(yv.z & 0xffffu); v[5] = bf2f(yv.z >> 16);
  v[6] = bf2f(yv.w & 0xffffu); v[7] = bf2f(yv.w >> 16);
  const float4* ap = (const float4*)(sf + c0);
  float4 a0 = ap[0], a1 = ap[1];
  const float4* shp = (const float4*)(sf + 256 + c0);
  float4 s0 = shp[0], s1 = shp[1];
  v[0] = a0.x * v[0] + s0.x; v[1] = a0.y * v[1] + s0.y;
  v[2] = a0.z * v[2] + s0.z; v[3] = a0.w * v[3] + s0.w;
  v[4] = a1.x * v[4] + s1.x; v[5] = a1.y * v[5] + s1.y;
  v[6] = a1.z * v[6] + s1.z; v[7] = a1.w * v[7] + s1.w;
  if (V >= 1) {
    const float4* kp = (const float4*)(skip + base);
    float4 k0 = kp[0], k1 = kp[1];
    v[0] += k0.x; v[1] += k0.y; v[2] += k0.z; v[3] += k0.w;
    v[4] += k1.x; v[5] += k1.y; v[6] += k1.z; v[7] += k1.w;
  }
#pragma unroll
  for (int i = 0; i < 8; ++i) v[i] = v[i] > 0.0f ? v[i] : 0.01f * v[i];
  if (V <= 1) {
    int d = t >> 10, h = (t >> 5) & 31, w = t & 31;
    int prow = (d + 1) * 1156 + (h + 1) * 34 + (w + 1);
    uint4 pk;
    pk.x = (u32)f2bf(v[0]) | ((u32)f2bf(v[1]) << 16);
    pk.y = (u32)f2bf(v[2]) | ((u32)f2bf(v[3]) << 16);
    pk.z = (u32)f2bf(v[4]) | ((u32)f2bf(v[5]) << 16);
    pk.w = (u32)f2bf(v[6]) | ((u32)f2bf(v[7]) << 16);
    *(uint4*)(pad + (size_t)prow * 256 + c0) = pk;
  }
  if (V == 1) {
    float4 o0 = {v[0], v[1], v[2], v[3]}, o1 = {v[4], v[5], v[6], v[7]};
    float4* fp = (float4*)(f32o + base);
    fp[0] = o0; fp[1] = o1;
  }
  if (V == 2) {
    uint4 pk;
    pk.x = (u32)f2bf(v[0]) | ((u32)f2bf(v[1]) << 16);
    pk.y = (u32)f2bf(v[2]) | ((u32)f2bf(v[3]) << 16);
    pk.z = (u32)f2bf(v[4]) | ((u32)f2bf(v[5]) << 16);
    pk.w = (u32)f2bf(v[6]) | ((u32)f2bf(v[7]) << 16);
    *(uint4*)(bfo + base) = pk;
  }
}

extern "C" void kernel_launch(void* const* d_in, const int* in_sizes, int n_in,
                              void* d_out, int out_size, void* d_ws, size_t ws_size,
                              hipStream_t stream) {
  (void)in_sizes; (void)n_in; (void)out_size; (void)ws_size;
  const float* x  = (const float*)d_in[0];
  const float* wg = (const float*)d_in[1];
  const float* w1 = (const float*)d_in[2];
  const float* b1 = (const float*)d_in[3];
  const float* w2 = (const float*)d_in[4];
  const float* b2 = (const float*)d_in[5];

  char* ws = (char*)d_ws;
  u16* tok    = (u16*)(ws + WS_TOK);
  float* xt   = (float*)(ws + WS_XT);
  float* xmct = (float*)(ws + WS_XMCT);
  float* gw   = (float*)(ws + WS_GATES);
  u32* tpos   = (u32*)(ws + WS_GATES + 0x80000ull);
  u32* perm   = (u32*)(ws + WS_PERM);
  u32* tbl    = (u32*)(ws + WS_TBL);
  u32* meta   = (u32*)(ws + WS_META);
  u32* bcnt   = (u32*)(ws + WS_BCNT);
  u32* boff   = (u32*)(ws + WS_BOFF);
  u32* selb   = (u32*)(ws + WS_SEL);
  u16* P1     = (u16*)(ws + WS_P1);
  u16* P2     = (u16*)(ws + WS_P2);
  u16* ybuf   = (u16*)(ws + WS_Y);
  u16* eo     = (u16*)(ws + WS_Y);   // eo lives in Y before convs start
  u16* r2b    = (u16*)(ws + WS_R2);
  u16* wrb    = (u16*)(ws + WS_WRB);
  u16* w1p    = (u16*)(ws + WS_W1P);
  u16* w2p    = (u16*)(ws + WS_W2P);
  u16* c8p    = (u16*)(ws + WS_C8P);
  float* part = (float*)(ws + WS_PART);
  float* sf   = (float*)(ws + WS_SF);
  float* auxp = (float*)(ws + WS_AUXP);
  float* outp = (float*)d_out;

  halo_k<<<4913, 256, 0, stream>>>(P1, P2);
  gate_k<<<128, 256, 0, stream>>>(x, wg, gw, selb, bcnt, auxp);
  trans_in_k<<<dim3(512, 4), 256, 0, stream>>>(x, xt, tok);
  pack_rb_k<<<1024, 256, 0, stream>>>((const float*)d_in[6], (const float*)d_in[10],
                                      (const float*)d_in[14], (const float*)d_in[18], wrb);
  pack_tr_k<<<dim3(16, 16), 256, 0, stream>>>(w1, w2, w1p, w2p);
  cvt_k<<<256, 256, 0, stream>>>((const float*)d_in[22], c8p, 65536);

  scan_k<<<1, 256, 0, stream>>>(bcnt, boff, tbl, meta, perm);
  scatter_k<<<128, 256, 0, stream>>>(selb, boff, perm, tpos);
  moe_gemm_k<<<520, 512, 0, stream>>>(tok, perm, tbl, meta, w1p, w2p, b1, b2, eo);
  combine_k<<<dim3(512, 4), 256, 0, stream>>>(xt, eo, gw, tpos, xmct, P1);

  // resblock 1
  conv_k<<<256, 512, 0, stream>>>(P1, wrb + 0 * 1769472, (const float*)d_in[7], ybuf, part);
  stats2_k<<<16, 256, 0, stream>>>(part, (const float*)d_in[8], (const float*)d_in[9], sf);
  bn_k<0><<<4096, 256, 0, stream>>>(ybuf, sf, nullptr, P2, nullptr, nullptr);
  conv_k<<<256, 512, 0, stream>>>(P2, wrb + 1 * 1769472, (const float*)d_in[11], ybuf, part);
  stats2_k<<<16, 256, 0, stream>>>(part, (const float*)d_in[12], (const float*)d_in[13], sf);
  bn_k<1><<<4096, 256, 0, stream>>>(ybuf, sf, xt, P1, xt, nullptr);

  // resblock 2
  conv_k<<<256, 512, 0, stream>>>(P1, wrb + 2 * 1769472, (const float*)d_in[15], ybuf, part);
  stats2_k<<<16, 256, 0, stream>>>(part, (const float*)d_in[16], (const float*)d_in[17], sf);
  bn_k<0><<<4096, 256, 0, stream>>>(ybuf, sf, nullptr, P2, nullptr, nullptr);
  conv_k<<<256, 512, 0, stream>>>(P2, wrb + 3 * 1769472, (const float*)d_in[19], ybuf, part);
  stats2_k<<<16, 256, 0, stream>>>(part, (const float*)d_in[20], (const float*)d_in[21], sf);
  bn_k<2><<<4096, 256, 0, stream>>>(ybuf, sf, xt, nullptr, nullptr, r2b);

  // final: out = xm + conv1x1(res)
  final_k<<<dim3(256, 2), 256, 0, stream>>>(r2b, c8p, (const float*)d_in[23], outp, xmct);
  aux_k<<<1, 64, 0, stream>>>(auxp, outp + 8388608);
}

// Round 10
// 670.444 us; speedup vs baseline: 1.0146x; 1.0146x over previous
//
#include <hip/hip_runtime.h>
#include <stdint.h>

typedef __attribute__((ext_vector_type(8))) short short8;
typedef __attribute__((ext_vector_type(4))) float f32x4;
typedef unsigned short u16;
typedef unsigned int u32;
typedef unsigned long long u64;

// ---------------- workspace layout (bytes) ----------------
#define WS_TOK   0ull           // tokens bf16 [32768][256]            16 MB
#define WS_XT    16777216ull    // x_t -> xm_tc -> r1 fp32 [T][C]      32 MB
#define WS_XMCT  50331648ull    // xm fp32 [C][T]                      32 MB
#define WS_GATES 83886080ull    // gw fp32 [T][2] | tpos u32 [T][2]
#define WS_H     84934656ull    // perm/meta/sel region (16 MB)
#define WS_P1    135266304ull   // padded bf16 [34^3][256]             19.2MB
#define WS_P2    155389952ull
#define WS_Y     175513600ull   // conv y bf16 [T][256] / eo bf16 [66560][256]
#define WS_R2    209068032ull   // r2 bf16 [T][256]
#define WS_WRB   225845248ull   // packed rb conv w bf16 [4][27][256][256]
#define WS_W1P   240001024ull
#define WS_W2P   241049600ull
#define WS_C8P   242098176ull
#define WS_PART  242229248ull   // bn partials [2][512][256] fp32 (1MB)
#define WS_SF    243277824ull   // bn scale/shift [2][256]
#define WS_AUXP  243279872ull   // aux partials [128][16]

#define WS_PERM  (WS_H + 0x00000ull)
#define WS_TBL   (WS_H + 0x60000ull)
#define WS_META  (WS_H + 0x70000ull)
#define WS_BCNT  (WS_H + 0x80000ull)
#define WS_BOFF  (WS_H + 0x90000ull)
#define WS_SEL   (WS_H + 0x100000ull)

__device__ __forceinline__ u16 f2bf(float f) {
  u32 x = __float_as_uint(f);
  u32 r = x + 0x7fffu + ((x >> 16) & 1u);
  return (u16)(r >> 16);
}
__device__ __forceinline__ float bf2f(u32 u) { return __uint_as_float(u << 16); }

// ---------------- transpose x [C][T] -> x_t fp32 + tokens bf16 [T][C] ----------------
__global__ void trans_in_k(const float* __restrict__ x, float* __restrict__ xt,
                           u16* __restrict__ tok) {
  __shared__ float ld[64][65];
  int tt = blockIdx.x, cc = blockIdx.y, tid = threadIdx.x;
#pragma unroll
  for (int k = 0; k < 16; ++k) {
    int idx = tid + k * 256;
    int cl = idx >> 6, j = idx & 63;
    ld[cl][j] = x[(size_t)(cc * 64 + cl) * 32768 + tt * 64 + j];
  }
  __syncthreads();
#pragma unroll
  for (int k = 0; k < 16; ++k) {
    int idx = tid + k * 256;
    int tl = idx >> 6, cl = idx & 63;
    float v = ld[cl][tl];
    size_t o = (size_t)(tt * 64 + tl) * 256 + cc * 64 + cl;
    xt[o] = v;
    tok[o] = f2bf(v);
  }
}

// ---------------- pack resblock conv weights ----------------
__global__ void pack_rb_k(const float* __restrict__ w0, const float* __restrict__ w1,
                          const float* __restrict__ w2, const float* __restrict__ w3,
                          u16* __restrict__ out) {
  __shared__ float ld[6912];
  int conv = blockIdx.x >> 8, blk = blockIdx.x & 255, tid = threadIdx.x;
  const float* src = conv == 0 ? w0 : conv == 1 ? w1 : conv == 2 ? w2 : w3;
  size_t base = (size_t)blk * 256 * 27;
#pragma unroll
  for (int k = 0; k < 27; ++k) ld[tid + k * 256] = src[base + tid + k * 256];
  __syncthreads();
  u16* dst = out + (size_t)conv * 27 * 65536;
  int n = blk * 256 + tid;
#pragma unroll
  for (int tap = 0; tap < 27; ++tap)
    dst[(size_t)tap * 65536 + n] = f2bf(ld[tid * 27 + tap]);
}

// ---------------- transpose-pack w1/w2 256x256 matrices to [N][K] bf16 ----------------
__global__ void pack_tr_k(const float* __restrict__ w1, const float* __restrict__ w2,
                          u16* __restrict__ w1p, u16* __restrict__ w2p) {
  __shared__ float ld[64][65];
  int m = blockIdx.y, tile = blockIdx.x, tid = threadIdx.x;
  const float* src = (m < 8) ? (w1 + (size_t)m * 65536) : (w2 + (size_t)(m - 8) * 65536);
  u16* dst = (m < 8) ? (w1p + (size_t)m * 65536) : (w2p + (size_t)(m - 8) * 65536);
  int r0 = (tile >> 2) * 64, c0 = (tile & 3) * 64;
#pragma unroll
  for (int k = 0; k < 16; ++k) {
    int idx = tid + k * 256;
    int rr = idx >> 6, cc = idx & 63;
    ld[rr][cc] = src[(size_t)(r0 + rr) * 256 + c0 + cc];
  }
  __syncthreads();
#pragma unroll
  for (int k = 0; k < 16; ++k) {
    int idx = tid + k * 256;
    int cc = idx >> 6, rr = idx & 63;
    dst[(size_t)(c0 + cc) * 256 + r0 + rr] = f2bf(ld[rr][cc]);
  }
}

__global__ void cvt_k(const float* __restrict__ in, u16* __restrict__ out, int n) {
  int i = blockIdx.x * 256 + threadIdx.x;
  if (i < n) out[i] = f2bf(in[i]);
}

// ---------------- zero halo rows of both padded buffers ----------------
__global__ void halo_k(u16* __restrict__ P1, u16* __restrict__ P2) {
  int gid = blockIdx.x * 256 + threadIdx.x;
  int r = gid >> 5, o = (gid & 31) << 3;
  if (r >= 39304) return;
  int d = r / 1156, rem = r - d * 1156, h = rem / 34, w = rem - h * 34;
  if (d >= 1 && d <= 32 && h >= 1 && h <= 32 && w >= 1 && w <= 32) return;
  uint4 z = {0u, 0u, 0u, 0u};
  *(uint4*)(P1 + (size_t)r * 256 + o) = z;
  *(uint4*)(P2 + (size_t)r * 256 + o) = z;
}

// ---------------- gating: reads x [C][T] (coalesced); softmax + top2 + aux ----------
__global__ void gate_k(const float* __restrict__ x, const float* __restrict__ wg,
                       float* __restrict__ gw, u32* __restrict__ sel,
                       u32* __restrict__ blk_cnt, float* __restrict__ auxp) {
  __shared__ float wgs[2048];
  __shared__ float ax[4][16];
  __shared__ u32 bc[4][8];
  int tid = threadIdx.x;
#pragma unroll
  for (int k = 0; k < 8; ++k) wgs[tid + k * 256] = wg[tid + k * 256];
  __syncthreads();
  int t = blockIdx.x * 256 + tid;
  int lane = tid & 63, wv = tid >> 6;
  float l[8] = {0, 0, 0, 0, 0, 0, 0, 0};
#pragma unroll 4
  for (int c = 0; c < 256; ++c) {
    float xv = x[(size_t)c * 32768 + t];
#pragma unroll
    for (int e = 0; e < 8; ++e) l[e] += xv * wgs[c * 8 + e];
  }
  float mx = l[0];
#pragma unroll
  for (int e = 1; e < 8; ++e) mx = fmaxf(mx, l[e]);
  float p[8], sum = 0.f;
#pragma unroll
  for (int e = 0; e < 8; ++e) { p[e] = __expf(l[e] - mx); sum += p[e]; }
  float inv = 1.0f / sum;
#pragma unroll
  for (int e = 0; e < 8; ++e) p[e] *= inv;
  int i0 = 0; float v0 = p[0];
#pragma unroll
  for (int e = 1; e < 8; ++e) if (p[e] > v0) { v0 = p[e]; i0 = e; }
  int i1 = -1; float v1 = -1.0f;
#pragma unroll
  for (int e = 0; e < 8; ++e) if (e != i0 && p[e] > v1) { v1 = p[e]; i1 = e; }
  float wsum = v0 + v1;
  gw[t * 2] = v0 / wsum;
  gw[t * 2 + 1] = v1 / wsum;
  sel[t] = (u32)i0 | ((u32)i1 << 4);
  u64 mm[8];
#pragma unroll
  for (int e = 0; e < 8; ++e) mm[e] = __ballot(i0 == e || i1 == e);
  if (lane == 0) {
#pragma unroll
    for (int e = 0; e < 8; ++e) bc[wv][e] = (u32)__popcll(mm[e]);
  }
#pragma unroll
  for (int e = 0; e < 8; ++e) {
    float ps = p[e];
    float cn = (e == i0 || e == i1) ? 1.0f : 0.0f;
    for (int o = 32; o; o >>= 1) { ps += __shfl_down(ps, o); cn += __shfl_down(cn, o); }
    if (lane == 0) { ax[wv][e] = ps; ax[wv][8 + e] = cn; }
  }
  __syncthreads();
  if (tid < 16)
    auxp[blockIdx.x * 16 + tid] = ax[0][tid] + ax[1][tid] + ax[2][tid] + ax[3][tid];
  if (tid < 8)
    blk_cnt[blockIdx.x * 8 + tid] = bc[0][tid] + bc[1][tid] + bc[2][tid] + bc[3][tid];
}

__global__ void aux_k(const float* __restrict__ auxp, float* __restrict__ out) {
  __shared__ float s[16];
  int i = threadIdx.x;
  if (i < 16) {
    float a = 0;
    for (int b = 0; b < 128; ++b) a += auxp[b * 16 + i];
    s[i] = a;
  }
  __syncthreads();
  if (i == 0) {
    float r = 0;
    for (int e = 0; e < 8; ++e)
      r += (s[8 + e] * (1.0f / 32768.0f)) * (s[e] * (1.0f / 32768.0f));
    out[0] = r * 8.0f;
  }
}

// ---------------- scan: block counts -> absolute offsets, chunk table, perm pads ----
__global__ void scan_k(const u32* __restrict__ blk_cnt, u32* __restrict__ blkoff,
                       u32* __restrict__ tbl, u32* __restrict__ meta,
                       u32* __restrict__ perm) {
  __shared__ u32 tot[8], base[8], nck[8], cbase[8];
  int tid = threadIdx.x;
  if (tid < 8) {
    u32 run = 0;
    for (int b = 0; b < 128; ++b) {
      blkoff[b * 8 + tid] = run;
      run += blk_cnt[b * 8 + tid];
    }
    tot[tid] = run;
  }
  __syncthreads();
  if (tid == 0) {
    u32 acc = 0, c = 0;
    for (int e = 0; e < 8; ++e) {
      base[e] = acc;
      u32 nc = (tot[e] + 127) >> 7;
      nck[e] = nc;
      cbase[e] = c;
      acc += nc << 7;
      c += nc;
    }
    meta[0] = c;
  }
  __syncthreads();
  for (int i = tid; i < 1024; i += 256) blkoff[i] += base[i & 7];
  if (tid < 8) {
    for (u32 k = 0; k < nck[tid]; ++k)
      tbl[cbase[tid] + k] = ((base[tid] + (k << 7)) << 4) | (u32)tid;
    for (u32 sl = base[tid] + tot[tid]; sl < base[tid] + (nck[tid] << 7); ++sl)
      perm[sl] = 0;
  }
}

// ---------------- scatter: deterministic positions via ballot ranks ----------------
__global__ void scatter_k(const u32* __restrict__ sel, const u32* __restrict__ blkoff,
                          u32* __restrict__ perm, u32* __restrict__ tpos) {
  __shared__ u32 wcnt[4][8];
  int tid = threadIdx.x, b = blockIdx.x;
  int lane = tid & 63, wv = tid >> 6;
  int t = b * 256 + tid;
  u32 s = sel[t];
  int i0 = s & 15, i1 = (s >> 4) & 15;
  u64 mm[8];
#pragma unroll
  for (int e = 0; e < 8; ++e) mm[e] = __ballot(i0 == e || i1 == e);
  if (lane == 0) {
#pragma unroll
    for (int e = 0; e < 8; ++e) wcnt[wv][e] = (u32)__popcll(mm[e]);
  }
  __syncthreads();
  u64 lt = (1ull << lane) - 1ull;
#pragma unroll
  for (int e = 0; e < 8; ++e) {
    bool is0 = (i0 == e), is1 = (i1 == e);
    if (is0 || is1) {
      u32 woff = 0;
#pragma unroll
      for (int w = 0; w < 4; ++w)
        if (w < wv) woff += wcnt[w][e];
      u32 pos = blkoff[b * 8 + e] + woff + (u32)__popcll(mm[e] & lt);
      perm[pos] = (u32)t;
      tpos[t * 2 + (is0 ? 0 : 1)] = pos;
    }
  }
}

// ---------------- sparse MoE GEMM: w-dbuf + Hs aliased onto tok region -------------
// LDS: [0,64K) tok -> Hs | [64K,96K) wbuf0 | [96K,128K) wbuf1. 1 sync per kc step.
__global__ __launch_bounds__(512, 2) void moe_gemm_k(
    const u16* __restrict__ tok, const u32* __restrict__ perm,
    const u32* __restrict__ tbl, const u32* __restrict__ meta,
    const u16* __restrict__ w1p, const u16* __restrict__ w2p,
    const float* __restrict__ b1, const float* __restrict__ b2,
    u16* __restrict__ eo) {
  __shared__ __attribute__((aligned(16))) unsigned char smem[131072];
  const int bid = blockIdx.x;
  if ((u32)bid >= meta[0]) return;
  const u32 ent = tbl[bid];
  const int e = (int)(ent & 15u);
  const int slot0 = (int)(ent >> 4);
  const int tid = threadIdx.x;
  const int lane = tid & 63;
  const int wv = tid >> 6;
  const int wr = (wv >> 2) * 64;
  const int wc = (wv & 3) * 64;
  const int fq = lane >> 4, fr = lane & 15;
  const u16* w1e = w1p + e * 65536;
  const u16* w2e = w2p + e * 65536;

  int woff[4];
#pragma unroll
  for (int it = 0; it < 4; ++it) {
    int s = tid + it * 512;
    int r = s >> 3;
    woff[it] = r * 256 + (((s & 7) ^ (r & 7)) << 3);
  }

  // prologue: gathered tok rows [128][256] + w1 kc0 -> wbuf0
#pragma unroll
  for (int it = 0; it < 8; ++it) {
    int s = tid + it * 512;
    int r = s >> 5, seg = s & 31;
    int cole = ((seg >> 3) << 6) + (((seg & 7) ^ (r & 7)) << 3);
    u32 rowtok = perm[slot0 + r];
    __builtin_amdgcn_global_load_lds(
        (const __attribute__((address_space(1))) u32*)(tok + (size_t)rowtok * 256 + cole),
        (__attribute__((address_space(3))) u32*)(smem + s * 16), 16, 0, 0);
  }
#pragma unroll
  for (int it = 0; it < 4; ++it)
    __builtin_amdgcn_global_load_lds(
        (const __attribute__((address_space(1))) u32*)(w1e + woff[it]),
        (__attribute__((address_space(3))) u32*)(smem + 65536 + (tid + it * 512) * 16),
        16, 0, 0);
  __syncthreads();

  // ---- GEMM1 (swapped): acc1[mc][nt] = w1-rows x tok-rows -> h^T frags ----
  f32x4 acc1[4][4];
#pragma unroll
  for (int mc = 0; mc < 4; ++mc)
#pragma unroll
    for (int nt = 0; nt < 4; ++nt) acc1[mc][nt] = (f32x4){0.f, 0.f, 0.f, 0.f};

#pragma unroll 1
  for (int kc = 0; kc < 4; ++kc) {
    const u16* nw = (kc < 3) ? (w1e + (kc + 1) * 64) : w2e;
    unsigned char* nb = smem + 65536 + (((kc + 1) & 1) * 32768);
#pragma unroll
    for (int it = 0; it < 4; ++it)
      __builtin_amdgcn_global_load_lds(
          (const __attribute__((address_space(1))) u32*)(nw + woff[it]),
          (__attribute__((address_space(3))) u32*)(nb + (tid + it * 512) * 16),
          16, 0, 0);
    const unsigned char* wb = smem + 65536 + ((kc & 1) * 32768);
#pragma unroll
    for (int khf = 0; khf < 2; ++khf) {
      short8 af1[4], bt[4];
#pragma unroll
      for (int mc = 0; mc < 4; ++mc) {
        int row = wc + mc * 16 + fr;
        int p = (khf * 4 + fq) ^ (row & 7);
        af1[mc] = *(const short8*)(wb + row * 128 + p * 16);
      }
#pragma unroll
      for (int nt = 0; nt < 4; ++nt) {
        int row = wr + nt * 16 + fr;
        int p = (khf * 4 + fq) ^ (row & 7);
        bt[nt] = *(const short8*)(smem + row * 512 + kc * 128 + p * 16);
      }
#pragma unroll
      for (int mc = 0; mc < 4; ++mc)
#pragma unroll
        for (int nt = 0; nt < 4; ++nt)
          acc1[mc][nt] = __builtin_amdgcn_mfma_f32_16x16x32_bf16(af1[mc], bt[nt], acc1[mc][nt], 0, 0, 0);
    }
    __syncthreads();
  }

  // epilogue: h = gelu(acc1 + b1[c]) -> Hs (aliases tok region; tok reads all done)
#pragma unroll
  for (int mc = 0; mc < 4; ++mc) {
    int k0 = wc + mc * 16 + fq * 4;
    float4 bv = *(const float4*)(b1 + e * 256 + k0);
#pragma unroll
    for (int nt = 0; nt < 4; ++nt) {
      int t = wr + nt * 16 + fr;
      u64 pk = 0;
#pragma unroll
      for (int j = 0; j < 4; ++j) {
        float v = acc1[mc][nt][j] + ((const float*)&bv)[j];
        float u = 1.5957691216057308f * (v + 0.044715f * v * v * v);
        float g = v / (1.0f + __expf(-u));
        pk |= (u64)f2bf(g) << (16 * j);
      }
      *(u64*)(smem + t * 512 + ((k0 * 2) ^ ((t & 7) << 4))) = pk;
    }
  }
  __syncthreads();  // Hs visible; wbuf0 already holds w2 kc0

  // ---- GEMM2: acc2[m][n] = h-rows x w2-rows ----
  f32x4 acc2[4][4];
#pragma unroll
  for (int m = 0; m < 4; ++m)
#pragma unroll
    for (int n = 0; n < 4; ++n) acc2[m][n] = (f32x4){0.f, 0.f, 0.f, 0.f};

#pragma unroll 1
  for (int kc = 0; kc < 4; ++kc) {
    if (kc < 3) {
      unsigned char* nb = smem + 65536 + (((kc + 1) & 1) * 32768);
      const u16* nw = w2e + (kc + 1) * 64;
#pragma unroll
      for (int it = 0; it < 4; ++it)
        __builtin_amdgcn_global_load_lds(
            (const __attribute__((address_space(1))) u32*)(nw + woff[it]),
            (__attribute__((address_space(3))) u32*)(nb + (tid + it * 512) * 16),
            16, 0, 0);
    }
    const unsigned char* wb = smem + 65536 + ((kc & 1) * 32768);
#pragma unroll
    for (int khf = 0; khf < 2; ++khf) {
      short8 af[4], bb[4];
#pragma unroll
      for (int m = 0; m < 4; ++m) {
        int row = wr + m * 16 + fr;
        int col = (kc * 128 + (khf * 4 + fq) * 16) ^ ((row & 7) << 4);
        af[m] = *(const short8*)(smem + row * 512 + col);
      }
#pragma unroll
      for (int n = 0; n < 4; ++n) {
        int row = wc + n * 16 + fr;
        int p = (khf * 4 + fq) ^ (row & 7);
        bb[n] = *(const short8*)(wb + row * 128 + p * 16);
      }
#pragma unroll
      for (int m = 0; m < 4; ++m)
#pragma unroll
        for (int n = 0; n < 4; ++n)
          acc2[m][n] = __builtin_amdgcn_mfma_f32_16x16x32_bf16(af[m], bb[n], acc2[m][n], 0, 0, 0);
    }
    __syncthreads();
  }

  float bs2[4];
#pragma unroll
  for (int n = 0; n < 4; ++n) bs2[n] = b2[e * 256 + wc + n * 16 + fr];
#pragma unroll
  for (int m = 0; m < 4; ++m)
#pragma unroll
    for (int j = 0; j < 4; ++j) {
      int rowslot = slot0 + wr + m * 16 + fq * 4 + j;
      u16* er = eo + (size_t)rowslot * 256 + wc;
#pragma unroll
      for (int n = 0; n < 4; ++n) er[n * 16 + fr] = f2bf(acc2[m][n][j] + bs2[n]);
    }
}

// ---------------- combine: xm = x + g0*eo[p0] + g1*eo[p1]; write xt/xmct/pad --------
__global__ void combine_k(float* __restrict__ xt, const u16* __restrict__ eo,
                          const float* __restrict__ gw, const u32* __restrict__ tpos,
                          float* __restrict__ xmct, u16* __restrict__ pad) {
  __shared__ float ld[64][65];
  __shared__ u32 pp[64][2];
  __shared__ float gg[64][2];
  int tt = blockIdx.x, cc = blockIdx.y, tid = threadIdx.x;
  if (tid < 128) {
    int tl = tid >> 1, s = tid & 1;
    int t = tt * 64 + tl;
    pp[tl][s] = tpos[t * 2 + s];
    gg[tl][s] = gw[t * 2 + s];
  }
  __syncthreads();
#pragma unroll
  for (int k = 0; k < 16; ++k) {
    int idx = tid + k * 256;
    int tl = idx >> 6, cl = idx & 63;
    int c = cc * 64 + cl;
    size_t o = (size_t)(tt * 64 + tl) * 256 + c;
    float e0 = bf2f(eo[(size_t)pp[tl][0] * 256 + c]);
    float e1 = bf2f(eo[(size_t)pp[tl][1] * 256 + c]);
    float v = xt[o] + gg[tl][0] * e0 + gg[tl][1] * e1;
    xt[o] = v;
    ld[tl][cl] = v;
    int t = tt * 64 + tl;
    int d = t >> 10, h = (t >> 5) & 31, w = t & 31;
    int prow = (d + 1) * 1156 + (h + 1) * 34 + (w + 1);
    pad[(size_t)prow * 256 + c] = f2bf(v);
  }
  __syncthreads();
#pragma unroll
  for (int k = 0; k < 16; ++k) {
    int idx = tid + k * 256;
    int cl = idx >> 6, tl = idx & 63;
    xmct[(size_t)(cc * 64 + cl) * 32768 + tt * 64 + tl] = ld[tl][cl];
  }
}

// ---------------- unified MFMA GEMM (convs + final 1x1), 2-phase double-buffer ------
// MODE 0: conv3x3x3 (XCD-swizzled ttile), y -> bf16 + fused BN partials
// MODE 3: final 1x1 conv, out[oc][t] = acc + bias + xmct[oc][t] (fp32)
template <int MODE>
__global__ __launch_bounds__(256, 2) void gemm_k(
    const u16* __restrict__ A, const u16* __restrict__ Bw,
    const float* __restrict__ bias, u16* __restrict__ yB,
    float* __restrict__ outF, const float* __restrict__ xmct,
    float* __restrict__ part) {
  __shared__ __attribute__((aligned(16))) unsigned char smem[65536];
  const int tid = threadIdx.x;
  const int bx = blockIdx.x;
  const int ttile = (MODE == 0) ? ((bx & 7) * 32 + (bx >> 3)) : bx;  // XCD-bijective
  const int ctile = blockIdx.y;
  const int lane = tid & 63;
  const int wv = tid >> 6;
  const int wr = (wv >> 1) << 6;
  const int wc = (wv & 1) << 6;
  const int fq = lane >> 4;
  const int fr = lane & 15;

  int aoff[4], boff[4];
#pragma unroll
  for (int it = 0; it < 4; ++it) {
    int s = tid + it * 256;
    int r = s >> 3;
    int lsg = (s & 7) ^ (r & 7);
    if (MODE == 0) {
      int dd = ttile >> 3;
      int h0 = (ttile & 7) << 2;
      int base = dd * 1156 + (h0 + (r >> 5)) * 34 + (r & 31);
      aoff[it] = base * 256 + lsg * 8;
    } else {
      aoff[it] = (ttile * 128 + r) * 256 + lsg * 8;
    }
    boff[it] = (ctile * 128 + r) * 256 + lsg * 8;
  }

  f32x4 acc[4][4];
#pragma unroll
  for (int m = 0; m < 4; ++m)
#pragma unroll
    for (int n = 0; n < 4; ++n) acc[m][n] = (f32x4){0.f, 0.f, 0.f, 0.f};

  const int nStep = (MODE == 0) ? 108 : 4;  // step = tap*4 + kc

  auto stage = [&](int s, int buf) {
    int tap = (MODE == 0) ? (s >> 2) : 0;
    int kc = s & 3;
    int atap = 0, btap = 0;
    if (MODE == 0) {
      atap = ((tap / 9) * 1156 + ((tap / 3) % 3) * 34 + (tap % 3)) * 256;
      btap = tap * 65536;
    }
    const u16* Ak = A + atap + kc * 64;
    const u16* Bk = Bw + btap + kc * 64;
    unsigned char* sb = smem + buf * 32768;
#pragma unroll
    for (int it = 0; it < 4; ++it) {
      __builtin_amdgcn_global_load_lds(
          (const __attribute__((address_space(1))) u32*)(Ak + aoff[it]),
          (__attribute__((address_space(3))) u32*)(sb + (tid + it * 256) * 16),
          16, 0, 0);
      __builtin_amdgcn_global_load_lds(
          (const __attribute__((address_space(1))) u32*)(Bk + boff[it]),
          (__attribute__((address_space(3))) u32*)(sb + 16384 + (tid + it * 256) * 16),
          16, 0, 0);
    }
  };

  auto compute = [&](int buf) {
    const unsigned char* sb = smem + buf * 32768;
#pragma unroll
    for (int khf = 0; khf < 2; ++khf) {
      short8 af[4], bb[4];
#pragma unroll
      for (int m = 0; m < 4; ++m) {
        int row = wr + m * 16 + fr;
        int p = (khf * 4 + fq) ^ (row & 7);
        af[m] = *(const short8*)(sb + row * 128 + p * 16);
      }
#pragma unroll
      for (int n = 0; n < 4; ++n) {
        int row = wc + n * 16 + fr;
        int p = (khf * 4 + fq) ^ (row & 7);
        bb[n] = *(const short8*)(sb + 16384 + row * 128 + p * 16);
      }
#pragma unroll
      for (int m = 0; m < 4; ++m)
#pragma unroll
        for (int n = 0; n < 4; ++n)
          acc[m][n] = __builtin_amdgcn_mfma_f32_16x16x32_bf16(af[m], bb[n], acc[m][n], 0, 0, 0);
    }
  };

  stage(0, 0);
  asm volatile("s_waitcnt vmcnt(0)" ::: "memory");
  __builtin_amdgcn_s_barrier();
  int cur = 0;
#pragma unroll 1
  for (int s = 0; s < nStep; ++s) {
    if (s + 1 < nStep) stage(s + 1, cur ^ 1);
    compute(cur);
    asm volatile("s_waitcnt vmcnt(0)" ::: "memory");
    __builtin_amdgcn_s_barrier();
    cur ^= 1;
  }

  float bs[4];
#pragma unroll
  for (int n = 0; n < 4; ++n) bs[n] = bias[ctile * 128 + wc + n * 16 + fr];

  if (MODE == 3) {
#pragma unroll
    for (int m = 0; m < 4; ++m) {
      int trow = ttile * 128 + wr + m * 16 + fq * 4;
#pragma unroll
      for (int n = 0; n < 4; ++n) {
        int oc = ctile * 128 + wc + n * 16 + fr;
        size_t o = (size_t)oc * 32768 + trow;
        float4 xv = *(const float4*)(xmct + o);
        float4 w;
        w.x = acc[m][n][0] + bs[n] + xv.x;
        w.y = acc[m][n][1] + bs[n] + xv.y;
        w.z = acc[m][n][2] + bs[n] + xv.z;
        w.w = acc[m][n][3] + bs[n] + xv.w;
        *(float4*)(outF + o) = w;
      }
    }
  } else {
    float sn[4] = {0, 0, 0, 0}, qn[4] = {0, 0, 0, 0};
#pragma unroll
    for (int m = 0; m < 4; ++m) {
#pragma unroll
      for (int j = 0; j < 4; ++j) {
        int t = ttile * 128 + wr + m * 16 + fq * 4 + j;
        u16* yr = yB + (size_t)t * 256 + ctile * 128 + wc;
#pragma unroll
        for (int n = 0; n < 4; ++n) {
          float v = acc[m][n][j] + bs[n];
          yr[n * 16 + fr] = f2bf(v);
          sn[n] += v;
          qn[n] += v * v;
        }
      }
    }
#pragma unroll
    for (int n = 0; n < 4; ++n) {
      float s = sn[n], q = qn[n];
      s += __shfl_xor(s, 16); s += __shfl_xor(s, 32);
      q += __shfl_xor(q, 16); q += __shfl_xor(q, 32);
      if (lane < 16) {
        int pi = (ttile * 2 + (wv >> 1)) * 256 + ctile * 128 + wc + n * 16 + fr;
        part[pi] = s;
        part[131072 + pi] = q;
      }
    }
  }
}

// ---------------- BN stats reduce: 16 blocks x 16 channels ----------------
__global__ void stats2_k(const float* __restrict__ part, const float* __restrict__ g,
                         const float* __restrict__ be, float* __restrict__ sf) {
  __shared__ float sred[16][16], qred[16][16];
  int tid = threadIdx.x;
  int cl = tid & 15, ch = tid >> 4;
  int c = blockIdx.x * 16 + cl;
  float s = 0, q = 0;
  for (int b = ch * 32; b < ch * 32 + 32; ++b) {
    s += part[b * 256 + c];
    q += part[131072 + b * 256 + c];
  }
  sred[ch][cl] = s;
  qred[ch][cl] = q;
  __syncthreads();
  if (ch == 0) {
    s = 0; q = 0;
#pragma unroll
    for (int k = 0; k < 16; ++k) { s += sred[k][cl]; q += qred[k][cl]; }
    float mean = s * (1.0f / 32768.0f);
    float var = q * (1.0f / 32768.0f) - mean * mean;
    float a = g[c] * rsqrtf(var + 1e-5f);
    sf[c] = a;
    sf[256 + c] = be[c] - mean * a;
  }
}

// ---------------- BN apply (+leaky, +skip); y is bf16 ----------------
template <int V>
__global__ void bn_k(const u16* __restrict__ y, const float* __restrict__ sf,
                     const float* __restrict__ skip, u16* __restrict__ pad,
                     float* __restrict__ f32o, u16* __restrict__ bfo) {
  int gid = blockIdx.x * 256 + threadIdx.x;
  int t = gid >> 5, c0 = (gid & 31) << 3;
  size_t base = (size_t)t * 256 + c0;
  float v[8];
  uint4 yv = *(const uint4*)(y + base);
  v[0] = bf2f(yv.x & 0xffffu); v[1] = bf2f(yv.x >> 16);
  v[2] = bf2f(yv.y & 0xffffu); v[3] = bf2f(yv.y >> 16);
  v[4] = bf2f(yv.z & 0xffffu); v[5] = bf2f(yv.z >> 16);
  v[6] = bf2f(yv.w & 0xffffu); v[7] = bf2f(yv.w >> 16);
  const float4* ap = (const float4*)(sf + c0);
  float4 a0 = ap[0], a1 = ap[1];
  const float4* shp = (const float4*)(sf + 256 + c0);
  float4 s0 = shp[0], s1 = shp[1];
  v[0] = a0.x * v[0] + s0.x; v[1] = a0.y * v[1] + s0.y;
  v[2] = a0.z * v[2] + s0.z; v[3] = a0.w * v[3] + s0.w;
  v[4] = a1.x * v[4] + s1.x; v[5] = a1.y * v[5] + s1.y;
  v[6] = a1.z * v[6] + s1.z; v[7] = a1.w * v[7] + s1.w;
  if (V >= 1) {
    const float4* kp = (const float4*)(skip + base);
    float4 k0 = kp[0], k1 = kp[1];
    v[0] += k0.x; v[1] += k0.y; v[2] += k0.z; v[3] += k0.w;
    v[4] += k1.x; v[5] += k1.y; v[6] += k1.z; v[7] += k1.w;
  }
#pragma unroll
  for (int i = 0; i < 8; ++i) v[i] = v[i] > 0.0f ? v[i] : 0.01f * v[i];
  if (V <= 1) {
    int d = t >> 10, h = (t >> 5) & 31, w = t & 31;
    int prow = (d + 1) * 1156 + (h + 1) * 34 + (w + 1);
    uint4 pk;
    pk.x = (u32)f2bf(v[0]) | ((u32)f2bf(v[1]) << 16);
    pk.y = (u32)f2bf(v[2]) | ((u32)f2bf(v[3]) << 16);
    pk.z = (u32)f2bf(v[4]) | ((u32)f2bf(v[5]) << 16);
    pk.w = (u32)f2bf(v[6]) | ((u32)f2bf(v[7]) << 16);
    *(uint4*)(pad + (size_t)prow * 256 + c0) = pk;
  }
  if (V == 1) {
    float4 o0 = {v[0], v[1], v[2], v[3]}, o1 = {v[4], v[5], v[6], v[7]};
    float4* fp = (float4*)(f32o + base);
    fp[0] = o0; fp[1] = o1;
  }
  if (V == 2) {
    uint4 pk;
    pk.x = (u32)f2bf(v[0]) | ((u32)f2bf(v[1]) << 16);
    pk.y = (u32)f2bf(v[2]) | ((u32)f2bf(v[3]) << 16);
    pk.z = (u32)f2bf(v[4]) | ((u32)f2bf(v[5]) << 16);
    pk.w = (u32)f2bf(v[6]) | ((u32)f2bf(v[7]) << 16);
    *(uint4*)(bfo + base) = pk;
  }
}

extern "C" void kernel_launch(void* const* d_in, const int* in_sizes, int n_in,
                              void* d_out, int out_size, void* d_ws, size_t ws_size,
                              hipStream_t stream) {
  (void)in_sizes; (void)n_in; (void)out_size; (void)ws_size;
  const float* x  = (const float*)d_in[0];
  const float* wg = (const float*)d_in[1];
  const float* w1 = (const float*)d_in[2];
  const float* b1 = (const float*)d_in[3];
  const float* w2 = (const float*)d_in[4];
  const float* b2 = (const float*)d_in[5];

  char* ws = (char*)d_ws;
  u16* tok    = (u16*)(ws + WS_TOK);
  float* xt   = (float*)(ws + WS_XT);
  float* xmct = (float*)(ws + WS_XMCT);
  float* gw   = (float*)(ws + WS_GATES);
  u32* tpos   = (u32*)(ws + WS_GATES + 0x80000ull);
  u32* perm   = (u32*)(ws + WS_PERM);
  u32* tbl    = (u32*)(ws + WS_TBL);
  u32* meta   = (u32*)(ws + WS_META);
  u32* bcnt   = (u32*)(ws + WS_BCNT);
  u32* boff   = (u32*)(ws + WS_BOFF);
  u32* selb   = (u32*)(ws + WS_SEL);
  u16* P1     = (u16*)(ws + WS_P1);
  u16* P2     = (u16*)(ws + WS_P2);
  u16* ybuf   = (u16*)(ws + WS_Y);
  u16* eo     = (u16*)(ws + WS_Y);   // eo lives in Y before convs start
  u16* r2b    = (u16*)(ws + WS_R2);
  u16* wrb    = (u16*)(ws + WS_WRB);
  u16* w1p    = (u16*)(ws + WS_W1P);
  u16* w2p    = (u16*)(ws + WS_W2P);
  u16* c8p    = (u16*)(ws + WS_C8P);
  float* part = (float*)(ws + WS_PART);
  float* sf   = (float*)(ws + WS_SF);
  float* auxp = (float*)(ws + WS_AUXP);
  float* outp = (float*)d_out;

  halo_k<<<4913, 256, 0, stream>>>(P1, P2);
  gate_k<<<128, 256, 0, stream>>>(x, wg, gw, selb, bcnt, auxp);
  trans_in_k<<<dim3(512, 4), 256, 0, stream>>>(x, xt, tok);
  pack_rb_k<<<1024, 256, 0, stream>>>((const float*)d_in[6], (const float*)d_in[10],
                                      (const float*)d_in[14], (const float*)d_in[18], wrb);
  pack_tr_k<<<dim3(16, 16), 256, 0, stream>>>(w1, w2, w1p, w2p);
  cvt_k<<<256, 256, 0, stream>>>((const float*)d_in[22], c8p, 65536);

  scan_k<<<1, 256, 0, stream>>>(bcnt, boff, tbl, meta, perm);
  scatter_k<<<128, 256, 0, stream>>>(selb, boff, perm, tpos);
  moe_gemm_k<<<520, 512, 0, stream>>>(tok, perm, tbl, meta, w1p, w2p, b1, b2, eo);
  combine_k<<<dim3(512, 4), 256, 0, stream>>>(xt, eo, gw, tpos, xmct, P1);

  // resblock 1
  gemm_k<0><<<dim3(256, 2), 256, 0, stream>>>(P1, wrb + 0 * 1769472, (const float*)d_in[7],
                                              ybuf, nullptr, nullptr, part);
  stats2_k<<<16, 256, 0, stream>>>(part, (const float*)d_in[8], (const float*)d_in[9], sf);
  bn_k<0><<<4096, 256, 0, stream>>>(ybuf, sf, nullptr, P2, nullptr, nullptr);
  gemm_k<0><<<dim3(256, 2), 256, 0, stream>>>(P2, wrb + 1 * 1769472, (const float*)d_in[11],
                                              ybuf, nullptr, nullptr, part);
  stats2_k<<<16, 256, 0, stream>>>(part, (const float*)d_in[12], (const float*)d_in[13], sf);
  bn_k<1><<<4096, 256, 0, stream>>>(ybuf, sf, xt, P1, xt, nullptr);

  // resblock 2
  gemm_k<0><<<dim3(256, 2), 256, 0, stream>>>(P1, wrb + 2 * 1769472, (const float*)d_in[15],
                                              ybuf, nullptr, nullptr, part);
  stats2_k<<<16, 256, 0, stream>>>(part, (const float*)d_in[16], (const float*)d_in[17], sf);
  bn_k<0><<<4096, 256, 0, stream>>>(ybuf, sf, nullptr, P2, nullptr, nullptr);
  gemm_k<0><<<dim3(256, 2), 256, 0, stream>>>(P2, wrb + 3 * 1769472, (const float*)d_in[19],
                                              ybuf, nullptr, nullptr, part);
  stats2_k<<<16, 256, 0, stream>>>(part, (const float*)d_in[20], (const float*)d_in[21], sf);
  bn_k<2><<<4096, 256, 0, stream>>>(ybuf, sf, xt, nullptr, nullptr, r2b);

  // final: out = xm + conv1x1(res)
  gemm_k<3><<<dim3(256, 2), 256, 0, stream>>>(r2b, c8p, (const float*)d_in[23], nullptr,
                                              outp, xmct, nullptr);
  aux_k<<<1, 64, 0, stream>>>(auxp, outp + 8388608);
}

// Round 11
// 653.187 us; speedup vs baseline: 1.0414x; 1.0264x over previous
//
#include <hip/hip_runtime.h>
#include <stdint.h>

typedef __attribute__((ext_vector_type(8))) short short8;
typedef __attribute__((ext_vector_type(4))) float f32x4;
typedef unsigned short u16;
typedef unsigned int u32;
typedef unsigned long long u64;

// ---------------- workspace layout (bytes) ----------------
#define WS_TOK   0ull           // tokens bf16 [32768][256]            16 MB
#define WS_XT    16777216ull    // x fp32 [T][C] (combine input only)  32 MB
#define WS_XMCT  50331648ull    // xm fp32 [C][T]                      32 MB
#define WS_GATES 83886080ull    // gw fp32 [T][2] | tpos u32 [T][2]
#define WS_H     84934656ull    // perm/meta/sel region (16 MB)
#define WS_P1    135266304ull   // padded bf16 [34^3][256]             19.2MB
#define WS_P2    155389952ull
#define WS_Y     175513600ull   // conv y bf16 [T][256] / eo bf16 [66560][256]
#define WS_R2    209068032ull   // r2 bf16 [T][256]
#define WS_WRB   225845248ull   // packed rb conv w bf16 [4][27][256][256]
#define WS_W1P   240001024ull
#define WS_W2P   241049600ull
#define WS_C8P   242098176ull
#define WS_PART  242229248ull   // bn partials [2][512][256] fp32 (1MB)
#define WS_SF    243277824ull   // bn scale/shift [2][256]
#define WS_AUXP  243279872ull   // aux partials [128][16]

#define WS_PERM  (WS_H + 0x00000ull)
#define WS_TBL   (WS_H + 0x60000ull)
#define WS_META  (WS_H + 0x70000ull)
#define WS_BCNT  (WS_H + 0x80000ull)
#define WS_BOFF  (WS_H + 0x90000ull)
#define WS_SEL   (WS_H + 0x100000ull)

__device__ __forceinline__ u16 f2bf(float f) {
  u32 x = __float_as_uint(f);
  u32 r = x + 0x7fffu + ((x >> 16) & 1u);
  return (u16)(r >> 16);
}
__device__ __forceinline__ float bf2f(u32 u) { return __uint_as_float(u << 16); }

// ---------------- transpose x [C][T] -> x_t fp32 + tokens bf16 [T][C] ----------------
__global__ void trans_in_k(const float* __restrict__ x, float* __restrict__ xt,
                           u16* __restrict__ tok) {
  __shared__ float ld[64][65];
  int tt = blockIdx.x, cc = blockIdx.y, tid = threadIdx.x;
#pragma unroll
  for (int k = 0; k < 16; ++k) {
    int idx = tid + k * 256;
    int cl = idx >> 6, j = idx & 63;
    ld[cl][j] = x[(size_t)(cc * 64 + cl) * 32768 + tt * 64 + j];
  }
  __syncthreads();
#pragma unroll
  for (int k = 0; k < 16; ++k) {
    int idx = tid + k * 256;
    int tl = idx >> 6, cl = idx & 63;
    float v = ld[cl][tl];
    size_t o = (size_t)(tt * 64 + tl) * 256 + cc * 64 + cl;
    xt[o] = v;
    tok[o] = f2bf(v);
  }
}

// ---------------- pack resblock conv weights ----------------
__global__ void pack_rb_k(const float* __restrict__ w0, const float* __restrict__ w1,
                          const float* __restrict__ w2, const float* __restrict__ w3,
                          u16* __restrict__ out) {
  __shared__ float ld[6912];
  int conv = blockIdx.x >> 8, blk = blockIdx.x & 255, tid = threadIdx.x;
  const float* src = conv == 0 ? w0 : conv == 1 ? w1 : conv == 2 ? w2 : w3;
  size_t base = (size_t)blk * 256 * 27;
#pragma unroll
  for (int k = 0; k < 27; ++k) ld[tid + k * 256] = src[base + tid + k * 256];
  __syncthreads();
  u16* dst = out + (size_t)conv * 27 * 65536;
  int n = blk * 256 + tid;
#pragma unroll
  for (int tap = 0; tap < 27; ++tap)
    dst[(size_t)tap * 65536 + n] = f2bf(ld[tid * 27 + tap]);
}

// ---------------- transpose-pack w1/w2 256x256 matrices to [N][K] bf16 ----------------
__global__ void pack_tr_k(const float* __restrict__ w1, const float* __restrict__ w2,
                          u16* __restrict__ w1p, u16* __restrict__ w2p) {
  __shared__ float ld[64][65];
  int m = blockIdx.y, tile = blockIdx.x, tid = threadIdx.x;
  const float* src = (m < 8) ? (w1 + (size_t)m * 65536) : (w2 + (size_t)(m - 8) * 65536);
  u16* dst = (m < 8) ? (w1p + (size_t)m * 65536) : (w2p + (size_t)(m - 8) * 65536);
  int r0 = (tile >> 2) * 64, c0 = (tile & 3) * 64;
#pragma unroll
  for (int k = 0; k < 16; ++k) {
    int idx = tid + k * 256;
    int rr = idx >> 6, cc = idx & 63;
    ld[rr][cc] = src[(size_t)(r0 + rr) * 256 + c0 + cc];
  }
  __syncthreads();
#pragma unroll
  for (int k = 0; k < 16; ++k) {
    int idx = tid + k * 256;
    int cc = idx >> 6, rr = idx & 63;
    dst[(size_t)(c0 + cc) * 256 + r0 + rr] = f2bf(ld[rr][cc]);
  }
}

__global__ void cvt_k(const float* __restrict__ in, u16* __restrict__ out, int n) {
  int i = blockIdx.x * 256 + threadIdx.x;
  if (i < n) out[i] = f2bf(in[i]);
}

// ---------------- zero halo rows of both padded buffers ----------------
__global__ void halo_k(u16* __restrict__ P1, u16* __restrict__ P2) {
  int gid = blockIdx.x * 256 + threadIdx.x;
  int r = gid >> 5, o = (gid & 31) << 3;
  if (r >= 39304) return;
  int d = r / 1156, rem = r - d * 1156, h = rem / 34, w = rem - h * 34;
  if (d >= 1 && d <= 32 && h >= 1 && h <= 32 && w >= 1 && w <= 32) return;
  uint4 z = {0u, 0u, 0u, 0u};
  *(uint4*)(P1 + (size_t)r * 256 + o) = z;
  *(uint4*)(P2 + (size_t)r * 256 + o) = z;
}

// ---------------- gating: reads x [C][T] (coalesced); softmax + top2 + aux ----------
__global__ void gate_k(const float* __restrict__ x, const float* __restrict__ wg,
                       float* __restrict__ gw, u32* __restrict__ sel,
                       u32* __restrict__ blk_cnt, float* __restrict__ auxp) {
  __shared__ float wgs[2048];
  __shared__ float ax[4][16];
  __shared__ u32 bc[4][8];
  int tid = threadIdx.x;
#pragma unroll
  for (int k = 0; k < 8; ++k) wgs[tid + k * 256] = wg[tid + k * 256];
  __syncthreads();
  int t = blockIdx.x * 256 + tid;
  int lane = tid & 63, wv = tid >> 6;
  float l[8] = {0, 0, 0, 0, 0, 0, 0, 0};
#pragma unroll 4
  for (int c = 0; c < 256; ++c) {
    float xv = x[(size_t)c * 32768 + t];
#pragma unroll
    for (int e = 0; e < 8; ++e) l[e] += xv * wgs[c * 8 + e];
  }
  float mx = l[0];
#pragma unroll
  for (int e = 1; e < 8; ++e) mx = fmaxf(mx, l[e]);
  float p[8], sum = 0.f;
#pragma unroll
  for (int e = 0; e < 8; ++e) { p[e] = __expf(l[e] - mx); sum += p[e]; }
  float inv = 1.0f / sum;
#pragma unroll
  for (int e = 0; e < 8; ++e) p[e] *= inv;
  int i0 = 0; float v0 = p[0];
#pragma unroll
  for (int e = 1; e < 8; ++e) if (p[e] > v0) { v0 = p[e]; i0 = e; }
  int i1 = -1; float v1 = -1.0f;
#pragma unroll
  for (int e = 0; e < 8; ++e) if (e != i0 && p[e] > v1) { v1 = p[e]; i1 = e; }
  float wsum = v0 + v1;
  gw[t * 2] = v0 / wsum;
  gw[t * 2 + 1] = v1 / wsum;
  sel[t] = (u32)i0 | ((u32)i1 << 4);
  u64 mm[8];
#pragma unroll
  for (int e = 0; e < 8; ++e) mm[e] = __ballot(i0 == e || i1 == e);
  if (lane == 0) {
#pragma unroll
    for (int e = 0; e < 8; ++e) bc[wv][e] = (u32)__popcll(mm[e]);
  }
#pragma unroll
  for (int e = 0; e < 8; ++e) {
    float ps = p[e];
    float cn = (e == i0 || e == i1) ? 1.0f : 0.0f;
    for (int o = 32; o; o >>= 1) { ps += __shfl_down(ps, o); cn += __shfl_down(cn, o); }
    if (lane == 0) { ax[wv][e] = ps; ax[wv][8 + e] = cn; }
  }
  __syncthreads();
  if (tid < 16)
    auxp[blockIdx.x * 16 + tid] = ax[0][tid] + ax[1][tid] + ax[2][tid] + ax[3][tid];
  if (tid < 8)
    blk_cnt[blockIdx.x * 8 + tid] = bc[0][tid] + bc[1][tid] + bc[2][tid] + bc[3][tid];
}

__global__ void aux_k(const float* __restrict__ auxp, float* __restrict__ out) {
  __shared__ float s[16];
  int i = threadIdx.x;
  if (i < 16) {
    float a = 0;
    for (int b = 0; b < 128; ++b) a += auxp[b * 16 + i];
    s[i] = a;
  }
  __syncthreads();
  if (i == 0) {
    float r = 0;
    for (int e = 0; e < 8; ++e)
      r += (s[8 + e] * (1.0f / 32768.0f)) * (s[e] * (1.0f / 32768.0f));
    out[0] = r * 8.0f;
  }
}

// ---------------- scan: block counts -> absolute offsets, chunk table, perm pads ----
__global__ void scan_k(const u32* __restrict__ blk_cnt, u32* __restrict__ blkoff,
                       u32* __restrict__ tbl, u32* __restrict__ meta,
                       u32* __restrict__ perm) {
  __shared__ u32 tot[8], base[8], nck[8], cbase[8];
  int tid = threadIdx.x;
  if (tid < 8) {
    u32 run = 0;
    for (int b = 0; b < 128; ++b) {
      blkoff[b * 8 + tid] = run;
      run += blk_cnt[b * 8 + tid];
    }
    tot[tid] = run;
  }
  __syncthreads();
  if (tid == 0) {
    u32 acc = 0, c = 0;
    for (int e = 0; e < 8; ++e) {
      base[e] = acc;
      u32 nc = (tot[e] + 127) >> 7;
      nck[e] = nc;
      cbase[e] = c;
      acc += nc << 7;
      c += nc;
    }
    meta[0] = c;
  }
  __syncthreads();
  for (int i = tid; i < 1024; i += 256) blkoff[i] += base[i & 7];
  if (tid < 8) {
    for (u32 k = 0; k < nck[tid]; ++k)
      tbl[cbase[tid] + k] = ((base[tid] + (k << 7)) << 4) | (u32)tid;
    for (u32 sl = base[tid] + tot[tid]; sl < base[tid] + (nck[tid] << 7); ++sl)
      perm[sl] = 0;
  }
}

// ---------------- scatter: deterministic positions via ballot ranks ----------------
__global__ void scatter_k(const u32* __restrict__ sel, const u32* __restrict__ blkoff,
                          u32* __restrict__ perm, u32* __restrict__ tpos) {
  __shared__ u32 wcnt[4][8];
  int tid = threadIdx.x, b = blockIdx.x;
  int lane = tid & 63, wv = tid >> 6;
  int t = b * 256 + tid;
  u32 s = sel[t];
  int i0 = s & 15, i1 = (s >> 4) & 15;
  u64 mm[8];
#pragma unroll
  for (int e = 0; e < 8; ++e) mm[e] = __ballot(i0 == e || i1 == e);
  if (lane == 0) {
#pragma unroll
    for (int e = 0; e < 8; ++e) wcnt[wv][e] = (u32)__popcll(mm[e]);
  }
  __syncthreads();
  u64 lt = (1ull << lane) - 1ull;
#pragma unroll
  for (int e = 0; e < 8; ++e) {
    bool is0 = (i0 == e), is1 = (i1 == e);
    if (is0 || is1) {
      u32 woff = 0;
#pragma unroll
      for (int w = 0; w < 4; ++w)
        if (w < wv) woff += wcnt[w][e];
      u32 pos = blkoff[b * 8 + e] + woff + (u32)__popcll(mm[e] & lt);
      perm[pos] = (u32)t;
      tpos[t * 2 + (is0 ? 0 : 1)] = pos;
    }
  }
}

// ---------------- sparse MoE GEMM: w-dbuf + Hs aliased onto tok region -------------
// LDS: [0,64K) tok -> Hs | [64K,96K) wbuf0 | [96K,128K) wbuf1. 1 sync per kc step.
__global__ __launch_bounds__(512, 2) void moe_gemm_k(
    const u16* __restrict__ tok, const u32* __restrict__ perm,
    const u32* __restrict__ tbl, const u32* __restrict__ meta,
    const u16* __restrict__ w1p, const u16* __restrict__ w2p,
    const float* __restrict__ b1, const float* __restrict__ b2,
    u16* __restrict__ eo) {
  __shared__ __attribute__((aligned(16))) unsigned char smem[131072];
  const int bid = blockIdx.x;
  if ((u32)bid >= meta[0]) return;
  const u32 ent = tbl[bid];
  const int e = (int)(ent & 15u);
  const int slot0 = (int)(ent >> 4);
  const int tid = threadIdx.x;
  const int lane = tid & 63;
  const int wv = tid >> 6;
  const int wr = (wv >> 2) * 64;
  const int wc = (wv & 3) * 64;
  const int fq = lane >> 4, fr = lane & 15;
  const u16* w1e = w1p + e * 65536;
  const u16* w2e = w2p + e * 65536;

  int woff[4];
#pragma unroll
  for (int it = 0; it < 4; ++it) {
    int s = tid + it * 512;
    int r = s >> 3;
    woff[it] = r * 256 + (((s & 7) ^ (r & 7)) << 3);
  }

  // prologue: gathered tok rows [128][256] + w1 kc0 -> wbuf0
#pragma unroll
  for (int it = 0; it < 8; ++it) {
    int s = tid + it * 512;
    int r = s >> 5, seg = s & 31;
    int cole = ((seg >> 3) << 6) + (((seg & 7) ^ (r & 7)) << 3);
    u32 rowtok = perm[slot0 + r];
    __builtin_amdgcn_global_load_lds(
        (const __attribute__((address_space(1))) u32*)(tok + (size_t)rowtok * 256 + cole),
        (__attribute__((address_space(3))) u32*)(smem + s * 16), 16, 0, 0);
  }
#pragma unroll
  for (int it = 0; it < 4; ++it)
    __builtin_amdgcn_global_load_lds(
        (const __attribute__((address_space(1))) u32*)(w1e + woff[it]),
        (__attribute__((address_space(3))) u32*)(smem + 65536 + (tid + it * 512) * 16),
        16, 0, 0);
  __syncthreads();

  // ---- GEMM1 (swapped): acc1[mc][nt] = w1-rows x tok-rows -> h^T frags ----
  f32x4 acc1[4][4];
#pragma unroll
  for (int mc = 0; mc < 4; ++mc)
#pragma unroll
    for (int nt = 0; nt < 4; ++nt) acc1[mc][nt] = (f32x4){0.f, 0.f, 0.f, 0.f};

#pragma unroll 1
  for (int kc = 0; kc < 4; ++kc) {
    const u16* nw = (kc < 3) ? (w1e + (kc + 1) * 64) : w2e;
    unsigned char* nb = smem + 65536 + (((kc + 1) & 1) * 32768);
#pragma unroll
    for (int it = 0; it < 4; ++it)
      __builtin_amdgcn_global_load_lds(
          (const __attribute__((address_space(1))) u32*)(nw + woff[it]),
          (__attribute__((address_space(3))) u32*)(nb + (tid + it * 512) * 16),
          16, 0, 0);
    const unsigned char* wb = smem + 65536 + ((kc & 1) * 32768);
#pragma unroll
    for (int khf = 0; khf < 2; ++khf) {
      short8 af1[4], bt[4];
#pragma unroll
      for (int mc = 0; mc < 4; ++mc) {
        int row = wc + mc * 16 + fr;
        int p = (khf * 4 + fq) ^ (row & 7);
        af1[mc] = *(const short8*)(wb + row * 128 + p * 16);
      }
#pragma unroll
      for (int nt = 0; nt < 4; ++nt) {
        int row = wr + nt * 16 + fr;
        int p = (khf * 4 + fq) ^ (row & 7);
        bt[nt] = *(const short8*)(smem + row * 512 + kc * 128 + p * 16);
      }
#pragma unroll
      for (int mc = 0; mc < 4; ++mc)
#pragma unroll
        for (int nt = 0; nt < 4; ++nt)
          acc1[mc][nt] = __builtin_amdgcn_mfma_f32_16x16x32_bf16(af1[mc], bt[nt], acc1[mc][nt], 0, 0, 0);
    }
    __syncthreads();
  }

  // epilogue: h = gelu(acc1 + b1[c]) -> Hs (aliases tok region; tok reads all done)
#pragma unroll
  for (int mc = 0; mc < 4; ++mc) {
    int k0 = wc + mc * 16 + fq * 4;
    float4 bv = *(const float4*)(b1 + e * 256 + k0);
#pragma unroll
    for (int nt = 0; nt < 4; ++nt) {
      int t = wr + nt * 16 + fr;
      u64 pk = 0;
#pragma unroll
      for (int j = 0; j < 4; ++j) {
        float v = acc1[mc][nt][j] + ((const float*)&bv)[j];
        float u = 1.5957691216057308f * (v + 0.044715f * v * v * v);
        float g = v / (1.0f + __expf(-u));
        pk |= (u64)f2bf(g) << (16 * j);
      }
      *(u64*)(smem + t * 512 + ((k0 * 2) ^ ((t & 7) << 4))) = pk;
    }
  }
  __syncthreads();  // Hs visible; wbuf0 already holds w2 kc0

  // ---- GEMM2: acc2[m][n] = h-rows x w2-rows ----
  f32x4 acc2[4][4];
#pragma unroll
  for (int m = 0; m < 4; ++m)
#pragma unroll
    for (int n = 0; n < 4; ++n) acc2[m][n] = (f32x4){0.f, 0.f, 0.f, 0.f};

#pragma unroll 1
  for (int kc = 0; kc < 4; ++kc) {
    if (kc < 3) {
      unsigned char* nb = smem + 65536 + (((kc + 1) & 1) * 32768);
      const u16* nw = w2e + (kc + 1) * 64;
#pragma unroll
      for (int it = 0; it < 4; ++it)
        __builtin_amdgcn_global_load_lds(
            (const __attribute__((address_space(1))) u32*)(nw + woff[it]),
            (__attribute__((address_space(3))) u32*)(nb + (tid + it * 512) * 16),
            16, 0, 0);
    }
    const unsigned char* wb = smem + 65536 + ((kc & 1) * 32768);
#pragma unroll
    for (int khf = 0; khf < 2; ++khf) {
      short8 af[4], bb[4];
#pragma unroll
      for (int m = 0; m < 4; ++m) {
        int row = wr + m * 16 + fr;
        int col = (kc * 128 + (khf * 4 + fq) * 16) ^ ((row & 7) << 4);
        af[m] = *(const short8*)(smem + row * 512 + col);
      }
#pragma unroll
      for (int n = 0; n < 4; ++n) {
        int row = wc + n * 16 + fr;
        int p = (khf * 4 + fq) ^ (row & 7);
        bb[n] = *(const short8*)(wb + row * 128 + p * 16);
      }
#pragma unroll
      for (int m = 0; m < 4; ++m)
#pragma unroll
        for (int n = 0; n < 4; ++n)
          acc2[m][n] = __builtin_amdgcn_mfma_f32_16x16x32_bf16(af[m], bb[n], acc2[m][n], 0, 0, 0);
    }
    __syncthreads();
  }

  float bs2[4];
#pragma unroll
  for (int n = 0; n < 4; ++n) bs2[n] = b2[e * 256 + wc + n * 16 + fr];
#pragma unroll
  for (int m = 0; m < 4; ++m)
#pragma unroll
    for (int j = 0; j < 4; ++j) {
      int rowslot = slot0 + wr + m * 16 + fq * 4 + j;
      u16* er = eo + (size_t)rowslot * 256 + wc;
#pragma unroll
      for (int n = 0; n < 4; ++n) er[n * 16 + fr] = f2bf(acc2[m][n][j] + bs2[n]);
    }
}

// ---------------- combine: xm = x + g0*eo[p0] + g1*eo[p1]; write xmct + pad ---------
__global__ void combine_k(const float* __restrict__ xt, const u16* __restrict__ eo,
                          const float* __restrict__ gw, const u32* __restrict__ tpos,
                          float* __restrict__ xmct, u16* __restrict__ pad) {
  __shared__ float ld[64][65];
  __shared__ u32 pp[64][2];
  __shared__ float gg[64][2];
  int tt = blockIdx.x, cc = blockIdx.y, tid = threadIdx.x;
  if (tid < 128) {
    int tl = tid >> 1, s = tid & 1;
    int t = tt * 64 + tl;
    pp[tl][s] = tpos[t * 2 + s];
    gg[tl][s] = gw[t * 2 + s];
  }
  __syncthreads();
#pragma unroll
  for (int k = 0; k < 16; ++k) {
    int idx = tid + k * 256;
    int tl = idx >> 6, cl = idx & 63;
    int c = cc * 64 + cl;
    size_t o = (size_t)(tt * 64 + tl) * 256 + c;
    float e0 = bf2f(eo[(size_t)pp[tl][0] * 256 + c]);
    float e1 = bf2f(eo[(size_t)pp[tl][1] * 256 + c]);
    float v = xt[o] + gg[tl][0] * e0 + gg[tl][1] * e1;
    ld[tl][cl] = v;
    int t = tt * 64 + tl;
    int d = t >> 10, h = (t >> 5) & 31, w = t & 31;
    int prow = (d + 1) * 1156 + (h + 1) * 34 + (w + 1);
    pad[(size_t)prow * 256 + c] = f2bf(v);
  }
  __syncthreads();
#pragma unroll
  for (int k = 0; k < 16; ++k) {
    int idx = tid + k * 256;
    int cl = idx >> 6, tl = idx & 63;
    xmct[(size_t)(cc * 64 + cl) * 32768 + tt * 64 + tl] = ld[tl][cl];
  }
}

// ---------------- unified MFMA GEMM (convs + final 1x1), 2-phase double-buffer ------
// MODE 0: conv3x3x3 (XCD-swizzled ttile), y -> bf16 + fused BN partials
// MODE 3: final 1x1 conv, out[oc][t] = acc + bias + xmct[oc][t] (fp32)
template <int MODE>
__global__ __launch_bounds__(256, 2) void gemm_k(
    const u16* __restrict__ A, const u16* __restrict__ Bw,
    const float* __restrict__ bias, u16* __restrict__ yB,
    float* __restrict__ outF, const float* __restrict__ xmct,
    float* __restrict__ part) {
  __shared__ __attribute__((aligned(16))) unsigned char smem[65536];
  const int tid = threadIdx.x;
  const int bx = blockIdx.x;
  const int ttile = (MODE == 0) ? ((bx & 7) * 32 + (bx >> 3)) : bx;  // XCD-bijective
  const int ctile = blockIdx.y;
  const int lane = tid & 63;
  const int wv = tid >> 6;
  const int wr = (wv >> 1) << 6;
  const int wc = (wv & 1) << 6;
  const int fq = lane >> 4;
  const int fr = lane & 15;

  int aoff[4], boff[4];
#pragma unroll
  for (int it = 0; it < 4; ++it) {
    int s = tid + it * 256;
    int r = s >> 3;
    int lsg = (s & 7) ^ (r & 7);
    if (MODE == 0) {
      int dd = ttile >> 3;
      int h0 = (ttile & 7) << 2;
      int base = dd * 1156 + (h0 + (r >> 5)) * 34 + (r & 31);
      aoff[it] = base * 256 + lsg * 8;
    } else {
      aoff[it] = (ttile * 128 + r) * 256 + lsg * 8;
    }
    boff[it] = (ctile * 128 + r) * 256 + lsg * 8;
  }

  f32x4 acc[4][4];
#pragma unroll
  for (int m = 0; m < 4; ++m)
#pragma unroll
    for (int n = 0; n < 4; ++n) acc[m][n] = (f32x4){0.f, 0.f, 0.f, 0.f};

  const int nStep = (MODE == 0) ? 108 : 4;  // step = tap*4 + kc

  auto stage = [&](int s, int buf) {
    int tap = (MODE == 0) ? (s >> 2) : 0;
    int kc = s & 3;
    int atap = 0, btap = 0;
    if (MODE == 0) {
      atap = ((tap / 9) * 1156 + ((tap / 3) % 3) * 34 + (tap % 3)) * 256;
      btap = tap * 65536;
    }
    const u16* Ak = A + atap + kc * 64;
    const u16* Bk = Bw + btap + kc * 64;
    unsigned char* sb = smem + buf * 32768;
#pragma unroll
    for (int it = 0; it < 4; ++it) {
      __builtin_amdgcn_global_load_lds(
          (const __attribute__((address_space(1))) u32*)(Ak + aoff[it]),
          (__attribute__((address_space(3))) u32*)(sb + (tid + it * 256) * 16),
          16, 0, 0);
      __builtin_amdgcn_global_load_lds(
          (const __attribute__((address_space(1))) u32*)(Bk + boff[it]),
          (__attribute__((address_space(3))) u32*)(sb + 16384 + (tid + it * 256) * 16),
          16, 0, 0);
    }
  };

  auto compute = [&](int buf) {
    const unsigned char* sb = smem + buf * 32768;
#pragma unroll
    for (int khf = 0; khf < 2; ++khf) {
      short8 af[4], bb[4];
#pragma unroll
      for (int m = 0; m < 4; ++m) {
        int row = wr + m * 16 + fr;
        int p = (khf * 4 + fq) ^ (row & 7);
        af[m] = *(const short8*)(sb + row * 128 + p * 16);
      }
#pragma unroll
      for (int n = 0; n < 4; ++n) {
        int row = wc + n * 16 + fr;
        int p = (khf * 4 + fq) ^ (row & 7);
        bb[n] = *(const short8*)(sb + 16384 + row * 128 + p * 16);
      }
#pragma unroll
      for (int m = 0; m < 4; ++m)
#pragma unroll
        for (int n = 0; n < 4; ++n)
          acc[m][n] = __builtin_amdgcn_mfma_f32_16x16x32_bf16(af[m], bb[n], acc[m][n], 0, 0, 0);
    }
  };

  stage(0, 0);
  asm volatile("s_waitcnt vmcnt(0)" ::: "memory");
  __builtin_amdgcn_s_barrier();
  int cur = 0;
#pragma unroll 1
  for (int s = 0; s < nStep; ++s) {
    if (s + 1 < nStep) stage(s + 1, cur ^ 1);
    compute(cur);
    asm volatile("s_waitcnt vmcnt(0)" ::: "memory");
    __builtin_amdgcn_s_barrier();
    cur ^= 1;
  }

  float bs[4];
#pragma unroll
  for (int n = 0; n < 4; ++n) bs[n] = bias[ctile * 128 + wc + n * 16 + fr];

  if (MODE == 3) {
#pragma unroll
    for (int m = 0; m < 4; ++m) {
      int trow = ttile * 128 + wr + m * 16 + fq * 4;
#pragma unroll
      for (int n = 0; n < 4; ++n) {
        int oc = ctile * 128 + wc + n * 16 + fr;
        size_t o = (size_t)oc * 32768 + trow;
        float4 xv = *(const float4*)(xmct + o);
        float4 w;
        w.x = acc[m][n][0] + bs[n] + xv.x;
        w.y = acc[m][n][1] + bs[n] + xv.y;
        w.z = acc[m][n][2] + bs[n] + xv.z;
        w.w = acc[m][n][3] + bs[n] + xv.w;
        *(float4*)(outF + o) = w;
      }
    }
  } else {
    float sn[4] = {0, 0, 0, 0}, qn[4] = {0, 0, 0, 0};
#pragma unroll
    for (int m = 0; m < 4; ++m) {
#pragma unroll
      for (int j = 0; j < 4; ++j) {
        int t = ttile * 128 + wr + m * 16 + fq * 4 + j;
        u16* yr = yB + (size_t)t * 256 + ctile * 128 + wc;
#pragma unroll
        for (int n = 0; n < 4; ++n) {
          float v = acc[m][n][j] + bs[n];
          yr[n * 16 + fr] = f2bf(v);
          sn[n] += v;
          qn[n] += v * v;
        }
      }
    }
#pragma unroll
    for (int n = 0; n < 4; ++n) {
      float s = sn[n], q = qn[n];
      s += __shfl_xor(s, 16); s += __shfl_xor(s, 32);
      q += __shfl_xor(q, 16); q += __shfl_xor(q, 32);
      if (lane < 16) {
        int pi = (ttile * 2 + (wv >> 1)) * 256 + ctile * 128 + wc + n * 16 + fr;
        part[pi] = s;
        part[131072 + pi] = q;
      }
    }
  }
}

// ---------------- BN stats reduce: 16 blocks x 16 channels ----------------
__global__ void stats2_k(const float* __restrict__ part, const float* __restrict__ g,
                         const float* __restrict__ be, float* __restrict__ sf) {
  __shared__ float sred[16][16], qred[16][16];
  int tid = threadIdx.x;
  int cl = tid & 15, ch = tid >> 4;
  int c = blockIdx.x * 16 + cl;
  float s = 0, q = 0;
  for (int b = ch * 32; b < ch * 32 + 32; ++b) {
    s += part[b * 256 + c];
    q += part[131072 + b * 256 + c];
  }
  sred[ch][cl] = s;
  qred[ch][cl] = q;
  __syncthreads();
  if (ch == 0) {
    s = 0; q = 0;
#pragma unroll
    for (int k = 0; k < 16; ++k) { s += sred[k][cl]; q += qred[k][cl]; }
    float mean = s * (1.0f / 32768.0f);
    float var = q * (1.0f / 32768.0f) - mean * mean;
    float a = g[c] * rsqrtf(var + 1e-5f);
    sf[c] = a;
    sf[256 + c] = be[c] - mean * a;
  }
}

// ---------------- BN apply (+leaky, +skip); y bf16; skip from PADDED bf16 ----------
// V0: no skip, write pad. V1: skip from skippad (padded), write pad (same buffer ok).
// V2: skip from skippad (padded), write flat bf16.
template <int V>
__global__ void bn_k(const u16* __restrict__ y, const float* __restrict__ sf,
                     const u16* __restrict__ skippad, u16* __restrict__ pad,
                     u16* __restrict__ bfo) {
  int gid = blockIdx.x * 256 + threadIdx.x;
  int t = gid >> 5, c0 = (gid & 31) << 3;
  size_t base = (size_t)t * 256 + c0;
  int d = t >> 10, h = (t >> 5) & 31, w = t & 31;
  int prow = (d + 1) * 1156 + (h + 1) * 34 + (w + 1);
  size_t pbase = (size_t)prow * 256 + c0;
  float v[8];
  uint4 yv = *(const uint4*)(y + base);
  v[0] = bf2f(yv.x & 0xffffu); v[1] = bf2f(yv.x >> 16);
  v[2] = bf2f(yv.y & 0xffffu); v[3] = bf2f(yv.y >> 16);
  v[4] = bf2f(yv.z & 0xffffu); v[5] = bf2f(yv.z >> 16);
  v[6] = bf2f(yv.w & 0xffffu); v[7] = bf2f(yv.w >> 16);
  const float4* ap = (const float4*)(sf + c0);
  float4 a0 = ap[0], a1 = ap[1];
  const float4* shp = (const float4*)(sf + 256 + c0);
  float4 s0 = shp[0], s1 = shp[1];
  v[0] = a0.x * v[0] + s0.x; v[1] = a0.y * v[1] + s0.y;
  v[2] = a0.z * v[2] + s0.z; v[3] = a0.w * v[3] + s0.w;
  v[4] = a1.x * v[4] + s1.x; v[5] = a1.y * v[5] + s1.y;
  v[6] = a1.z * v[6] + s1.z; v[7] = a1.w * v[7] + s1.w;
  if (V >= 1) {
    uint4 kv = *(const uint4*)(skippad + pbase);
    v[0] += bf2f(kv.x & 0xffffu); v[1] += bf2f(kv.x >> 16);
    v[2] += bf2f(kv.y & 0xffffu); v[3] += bf2f(kv.y >> 16);
    v[4] += bf2f(kv.z & 0xffffu); v[5] += bf2f(kv.z >> 16);
    v[6] += bf2f(kv.w & 0xffffu); v[7] += bf2f(kv.w >> 16);
  }
#pragma unroll
  for (int i = 0; i < 8; ++i) v[i] = v[i] > 0.0f ? v[i] : 0.01f * v[i];
  uint4 pk;
  pk.x = (u32)f2bf(v[0]) | ((u32)f2bf(v[1]) << 16);
  pk.y = (u32)f2bf(v[2]) | ((u32)f2bf(v[3]) << 16);
  pk.z = (u32)f2bf(v[4]) | ((u32)f2bf(v[5]) << 16);
  pk.w = (u32)f2bf(v[6]) | ((u32)f2bf(v[7]) << 16);
  if (V <= 1) *(uint4*)(pad + pbase) = pk;
  if (V == 2) *(uint4*)(bfo + base) = pk;
}

extern "C" void kernel_launch(void* const* d_in, const int* in_sizes, int n_in,
                              void* d_out, int out_size, void* d_ws, size_t ws_size,
                              hipStream_t stream) {
  (void)in_sizes; (void)n_in; (void)out_size; (void)ws_size;
  const float* x  = (const float*)d_in[0];
  const float* wg = (const float*)d_in[1];
  const float* w1 = (const float*)d_in[2];
  const float* b1 = (const float*)d_in[3];
  const float* w2 = (const float*)d_in[4];
  const float* b2 = (const float*)d_in[5];

  char* ws = (char*)d_ws;
  u16* tok    = (u16*)(ws + WS_TOK);
  float* xt   = (float*)(ws + WS_XT);
  float* xmct = (float*)(ws + WS_XMCT);
  float* gw   = (float*)(ws + WS_GATES);
  u32* tpos   = (u32*)(ws + WS_GATES + 0x80000ull);
  u32* perm   = (u32*)(ws + WS_PERM);
  u32* tbl    = (u32*)(ws + WS_TBL);
  u32* meta   = (u32*)(ws + WS_META);
  u32* bcnt   = (u32*)(ws + WS_BCNT);
  u32* boff   = (u32*)(ws + WS_BOFF);
  u32* selb   = (u32*)(ws + WS_SEL);
  u16* P1     = (u16*)(ws + WS_P1);
  u16* P2     = (u16*)(ws + WS_P2);
  u16* ybuf   = (u16*)(ws + WS_Y);
  u16* eo     = (u16*)(ws + WS_Y);   // eo lives in Y before convs start
  u16* r2b    = (u16*)(ws + WS_R2);
  u16* wrb    = (u16*)(ws + WS_WRB);
  u16* w1p    = (u16*)(ws + WS_W1P);
  u16* w2p    = (u16*)(ws + WS_W2P);
  u16* c8p    = (u16*)(ws + WS_C8P);
  float* part = (float*)(ws + WS_PART);
  float* sf   = (float*)(ws + WS_SF);
  float* auxp = (float*)(ws + WS_AUXP);
  float* outp = (float*)d_out;

  halo_k<<<4913, 256, 0, stream>>>(P1, P2);
  gate_k<<<128, 256, 0, stream>>>(x, wg, gw, selb, bcnt, auxp);
  trans_in_k<<<dim3(512, 4), 256, 0, stream>>>(x, xt, tok);
  pack_rb_k<<<1024, 256, 0, stream>>>((const float*)d_in[6], (const float*)d_in[10],
                                      (const float*)d_in[14], (const float*)d_in[18], wrb);
  pack_tr_k<<<dim3(16, 16), 256, 0, stream>>>(w1, w2, w1p, w2p);
  cvt_k<<<256, 256, 0, stream>>>((const float*)d_in[22], c8p, 65536);

  scan_k<<<1, 256, 0, stream>>>(bcnt, boff, tbl, meta, perm);
  scatter_k<<<128, 256, 0, stream>>>(selb, boff, perm, tpos);
  moe_gemm_k<<<520, 512, 0, stream>>>(tok, perm, tbl, meta, w1p, w2p, b1, b2, eo);
  combine_k<<<dim3(512, 4), 256, 0, stream>>>(xt, eo, gw, tpos, xmct, P1);

  // resblock 1 (P1 holds xm padded; skip chain lives in P1 as bf16)
  gemm_k<0><<<dim3(256, 2), 256, 0, stream>>>(P1, wrb + 0 * 1769472, (const float*)d_in[7],
                                              ybuf, nullptr, nullptr, part);
  stats2_k<<<16, 256, 0, stream>>>(part, (const float*)d_in[8], (const float*)d_in[9], sf);
  bn_k<0><<<4096, 256, 0, stream>>>(ybuf, sf, nullptr, P2, nullptr);
  gemm_k<0><<<dim3(256, 2), 256, 0, stream>>>(P2, wrb + 1 * 1769472, (const float*)d_in[11],
                                              ybuf, nullptr, nullptr, part);
  stats2_k<<<16, 256, 0, stream>>>(part, (const float*)d_in[12], (const float*)d_in[13], sf);
  bn_k<1><<<4096, 256, 0, stream>>>(ybuf, sf, P1, P1, nullptr);  // r1 = bn+xm(P1) -> P1

  // resblock 2 (P1 holds r1 padded)
  gemm_k<0><<<dim3(256, 2), 256, 0, stream>>>(P1, wrb + 2 * 1769472, (const float*)d_in[15],
                                              ybuf, nullptr, nullptr, part);
  stats2_k<<<16, 256, 0, stream>>>(part, (const float*)d_in[16], (const float*)d_in[17], sf);
  bn_k<0><<<4096, 256, 0, stream>>>(ybuf, sf, nullptr, P2, nullptr);
  gemm_k<0><<<dim3(256, 2), 256, 0, stream>>>(P2, wrb + 3 * 1769472, (const float*)d_in[19],
                                              ybuf, nullptr, nullptr, part);
  stats2_k<<<16, 256, 0, stream>>>(part, (const float*)d_in[20], (const float*)d_in[21], sf);
  bn_k<2><<<4096, 256, 0, stream>>>(ybuf, sf, P1, nullptr, r2b);  // r2 = bn+r1(P1) -> flat

  // final: out = xm + conv1x1(res)
  gemm_k<3><<<dim3(256, 2), 256, 0, stream>>>(r2b, c8p, (const float*)d_in[23], nullptr,
                                              outp, xmct, nullptr);
  aux_k<<<1, 64, 0, stream>>>(auxp, outp + 8388608);
}

// Round 12
// 624.312 us; speedup vs baseline: 1.0896x; 1.0462x over previous
//
#include <hip/hip_runtime.h>
#include <stdint.h>

typedef __attribute__((ext_vector_type(8))) short short8;
typedef __attribute__((ext_vector_type(4))) float f32x4;
typedef unsigned short u16;
typedef unsigned int u32;
typedef unsigned long long u64;

// ---------------- workspace layout (bytes) ----------------
#define WS_TOK   0ull           // tokens bf16 [32768][256]            16 MB
#define WS_XT    16777216ull    // (free)
#define WS_XMCT  50331648ull    // xm bf16 [C][T]                      16.7 MB
#define WS_GATES 83886080ull    // gw fp32 [T][2] | tpos u32 [T][2]
#define WS_H     84934656ull    // perm/meta/sel region (16 MB)
#define WS_P1    135266304ull   // padded bf16 [34^3][256]             19.2MB
#define WS_P2    155389952ull
#define WS_Y     175513600ull   // conv y bf16 [T][256] / eo bf16 [66560][256]
#define WS_R2    209068032ull   // r2 bf16 [T][256]
#define WS_WRB   225845248ull   // packed rb conv w bf16 [4][27][256][256]
#define WS_W1P   240001024ull
#define WS_W2P   241049600ull
#define WS_C8P   242098176ull
#define WS_PART  242229248ull   // bn partials [2][512][256] fp32 (1MB)
#define WS_SF    243277824ull   // bn scale/shift [2][256]
#define WS_AUXP  243279872ull   // aux partials [128][16]

#define WS_PERM  (WS_H + 0x00000ull)
#define WS_TBL   (WS_H + 0x60000ull)
#define WS_META  (WS_H + 0x70000ull)
#define WS_BCNT  (WS_H + 0x80000ull)
#define WS_BOFF  (WS_H + 0x90000ull)
#define WS_SEL   (WS_H + 0x100000ull)

__device__ __forceinline__ u16 f2bf(float f) {
  u32 x = __float_as_uint(f);
  u32 r = x + 0x7fffu + ((x >> 16) & 1u);
  return (u16)(r >> 16);
}
__device__ __forceinline__ float bf2f(u32 u) { return __uint_as_float(u << 16); }

// ---------------- transpose x [C][T] -> tokens bf16 [T][C] ----------------
__global__ void trans_in_k(const float* __restrict__ x, u16* __restrict__ tok) {
  __shared__ float ld[64][65];
  int tt = blockIdx.x, cc = blockIdx.y, tid = threadIdx.x;
#pragma unroll
  for (int k = 0; k < 16; ++k) {
    int idx = tid + k * 256;
    int cl = idx >> 6, j = idx & 63;
    ld[cl][j] = x[(size_t)(cc * 64 + cl) * 32768 + tt * 64 + j];
  }
  __syncthreads();
#pragma unroll
  for (int k = 0; k < 16; ++k) {
    int idx = tid + k * 256;
    int tl = idx >> 6, cl = idx & 63;
    size_t o = (size_t)(tt * 64 + tl) * 256 + cc * 64 + cl;
    tok[o] = f2bf(ld[cl][tl]);
  }
}

// ---------------- pack resblock conv weights ----------------
__global__ void pack_rb_k(const float* __restrict__ w0, const float* __restrict__ w1,
                          const float* __restrict__ w2, const float* __restrict__ w3,
                          u16* __restrict__ out) {
  __shared__ float ld[6912];
  int conv = blockIdx.x >> 8, blk = blockIdx.x & 255, tid = threadIdx.x;
  const float* src = conv == 0 ? w0 : conv == 1 ? w1 : conv == 2 ? w2 : w3;
  size_t base = (size_t)blk * 256 * 27;
#pragma unroll
  for (int k = 0; k < 27; ++k) ld[tid + k * 256] = src[base + tid + k * 256];
  __syncthreads();
  u16* dst = out + (size_t)conv * 27 * 65536;
  int n = blk * 256 + tid;
#pragma unroll
  for (int tap = 0; tap < 27; ++tap)
    dst[(size_t)tap * 65536 + n] = f2bf(ld[tid * 27 + tap]);
}

// ---------------- transpose-pack w1/w2 256x256 matrices to [N][K] bf16 ----------------
__global__ void pack_tr_k(const float* __restrict__ w1, const float* __restrict__ w2,
                          u16* __restrict__ w1p, u16* __restrict__ w2p) {
  __shared__ float ld[64][65];
  int m = blockIdx.y, tile = blockIdx.x, tid = threadIdx.x;
  const float* src = (m < 8) ? (w1 + (size_t)m * 65536) : (w2 + (size_t)(m - 8) * 65536);
  u16* dst = (m < 8) ? (w1p + (size_t)m * 65536) : (w2p + (size_t)(m - 8) * 65536);
  int r0 = (tile >> 2) * 64, c0 = (tile & 3) * 64;
#pragma unroll
  for (int k = 0; k < 16; ++k) {
    int idx = tid + k * 256;
    int rr = idx >> 6, cc = idx & 63;
    ld[rr][cc] = src[(size_t)(r0 + rr) * 256 + c0 + cc];
  }
  __syncthreads();
#pragma unroll
  for (int k = 0; k < 16; ++k) {
    int idx = tid + k * 256;
    int cc = idx >> 6, rr = idx & 63;
    dst[(size_t)(c0 + cc) * 256 + r0 + rr] = f2bf(ld[rr][cc]);
  }
}

__global__ void cvt_k(const float* __restrict__ in, u16* __restrict__ out, int n) {
  int i = blockIdx.x * 256 + threadIdx.x;
  if (i < n) out[i] = f2bf(in[i]);
}

// ---------------- zero halo rows of both padded buffers ----------------
__global__ void halo_k(u16* __restrict__ P1, u16* __restrict__ P2) {
  int gid = blockIdx.x * 256 + threadIdx.x;
  int r = gid >> 5, o = (gid & 31) << 3;
  if (r >= 39304) return;
  int d = r / 1156, rem = r - d * 1156, h = rem / 34, w = rem - h * 34;
  if (d >= 1 && d <= 32 && h >= 1 && h <= 32 && w >= 1 && w <= 32) return;
  uint4 z = {0u, 0u, 0u, 0u};
  *(uint4*)(P1 + (size_t)r * 256 + o) = z;
  *(uint4*)(P2 + (size_t)r * 256 + o) = z;
}

// ---------------- gating: reads x [C][T] (coalesced); softmax + top2 + aux ----------
__global__ void gate_k(const float* __restrict__ x, const float* __restrict__ wg,
                       float* __restrict__ gw, u32* __restrict__ sel,
                       u32* __restrict__ blk_cnt, float* __restrict__ auxp) {
  __shared__ float wgs[2048];
  __shared__ float ax[4][16];
  __shared__ u32 bc[4][8];
  int tid = threadIdx.x;
#pragma unroll
  for (int k = 0; k < 8; ++k) wgs[tid + k * 256] = wg[tid + k * 256];
  __syncthreads();
  int t = blockIdx.x * 256 + tid;
  int lane = tid & 63, wv = tid >> 6;
  float l[8] = {0, 0, 0, 0, 0, 0, 0, 0};
#pragma unroll 4
  for (int c = 0; c < 256; ++c) {
    float xv = x[(size_t)c * 32768 + t];
#pragma unroll
    for (int e = 0; e < 8; ++e) l[e] += xv * wgs[c * 8 + e];
  }
  float mx = l[0];
#pragma unroll
  for (int e = 1; e < 8; ++e) mx = fmaxf(mx, l[e]);
  float p[8], sum = 0.f;
#pragma unroll
  for (int e = 0; e < 8; ++e) { p[e] = __expf(l[e] - mx); sum += p[e]; }
  float inv = 1.0f / sum;
#pragma unroll
  for (int e = 0; e < 8; ++e) p[e] *= inv;
  int i0 = 0; float v0 = p[0];
#pragma unroll
  for (int e = 1; e < 8; ++e) if (p[e] > v0) { v0 = p[e]; i0 = e; }
  int i1 = -1; float v1 = -1.0f;
#pragma unroll
  for (int e = 0; e < 8; ++e) if (e != i0 && p[e] > v1) { v1 = p[e]; i1 = e; }
  float wsum = v0 + v1;
  gw[t * 2] = v0 / wsum;
  gw[t * 2 + 1] = v1 / wsum;
  sel[t] = (u32)i0 | ((u32)i1 << 4);
  u64 mm[8];
#pragma unroll
  for (int e = 0; e < 8; ++e) mm[e] = __ballot(i0 == e || i1 == e);
  if (lane == 0) {
#pragma unroll
    for (int e = 0; e < 8; ++e) bc[wv][e] = (u32)__popcll(mm[e]);
  }
#pragma unroll
  for (int e = 0; e < 8; ++e) {
    float ps = p[e];
    float cn = (e == i0 || e == i1) ? 1.0f : 0.0f;
    for (int o = 32; o; o >>= 1) { ps += __shfl_down(ps, o); cn += __shfl_down(cn, o); }
    if (lane == 0) { ax[wv][e] = ps; ax[wv][8 + e] = cn; }
  }
  __syncthreads();
  if (tid < 16)
    auxp[blockIdx.x * 16 + tid] = ax[0][tid] + ax[1][tid] + ax[2][tid] + ax[3][tid];
  if (tid < 8)
    blk_cnt[blockIdx.x * 8 + tid] = bc[0][tid] + bc[1][tid] + bc[2][tid] + bc[3][tid];
}

__global__ void aux_k(const float* __restrict__ auxp, float* __restrict__ out) {
  __shared__ float s[16];
  int i = threadIdx.x;
  if (i < 16) {
    float a = 0;
    for (int b = 0; b < 128; ++b) a += auxp[b * 16 + i];
    s[i] = a;
  }
  __syncthreads();
  if (i == 0) {
    float r = 0;
    for (int e = 0; e < 8; ++e)
      r += (s[8 + e] * (1.0f / 32768.0f)) * (s[e] * (1.0f / 32768.0f));
    out[0] = r * 8.0f;
  }
}

// ---------------- scan: block counts -> absolute offsets, chunk table, perm pads ----
__global__ void scan_k(const u32* __restrict__ blk_cnt, u32* __restrict__ blkoff,
                       u32* __restrict__ tbl, u32* __restrict__ meta,
                       u32* __restrict__ perm) {
  __shared__ u32 tot[8], base[8], nck[8], cbase[8];
  int tid = threadIdx.x;
  if (tid < 8) {
    u32 run = 0;
    for (int b = 0; b < 128; ++b) {
      blkoff[b * 8 + tid] = run;
      run += blk_cnt[b * 8 + tid];
    }
    tot[tid] = run;
  }
  __syncthreads();
  if (tid == 0) {
    u32 acc = 0, c = 0;
    for (int e = 0; e < 8; ++e) {
      base[e] = acc;
      u32 nc = (tot[e] + 127) >> 7;
      nck[e] = nc;
      cbase[e] = c;
      acc += nc << 7;
      c += nc;
    }
    meta[0] = c;
  }
  __syncthreads();
  for (int i = tid; i < 1024; i += 256) blkoff[i] += base[i & 7];
  if (tid < 8) {
    for (u32 k = 0; k < nck[tid]; ++k)
      tbl[cbase[tid] + k] = ((base[tid] + (k << 7)) << 4) | (u32)tid;
    for (u32 sl = base[tid] + tot[tid]; sl < base[tid] + (nck[tid] << 7); ++sl)
      perm[sl] = 0;
  }
}

// ---------------- scatter: deterministic positions via ballot ranks ----------------
__global__ void scatter_k(const u32* __restrict__ sel, const u32* __restrict__ blkoff,
                          u32* __restrict__ perm, u32* __restrict__ tpos) {
  __shared__ u32 wcnt[4][8];
  int tid = threadIdx.x, b = blockIdx.x;
  int lane = tid & 63, wv = tid >> 6;
  int t = b * 256 + tid;
  u32 s = sel[t];
  int i0 = s & 15, i1 = (s >> 4) & 15;
  u64 mm[8];
#pragma unroll
  for (int e = 0; e < 8; ++e) mm[e] = __ballot(i0 == e || i1 == e);
  if (lane == 0) {
#pragma unroll
    for (int e = 0; e < 8; ++e) wcnt[wv][e] = (u32)__popcll(mm[e]);
  }
  __syncthreads();
  u64 lt = (1ull << lane) - 1ull;
#pragma unroll
  for (int e = 0; e < 8; ++e) {
    bool is0 = (i0 == e), is1 = (i1 == e);
    if (is0 || is1) {
      u32 woff = 0;
#pragma unroll
      for (int w = 0; w < 4; ++w)
        if (w < wv) woff += wcnt[w][e];
      u32 pos = blkoff[b * 8 + e] + woff + (u32)__popcll(mm[e] & lt);
      perm[pos] = (u32)t;
      tpos[t * 2 + (is0 ? 0 : 1)] = pos;
    }
  }
}

// ---------------- sparse MoE GEMM: w-dbuf + Hs aliased onto tok region -------------
// LDS: [0,64K) tok -> Hs | [64K,96K) wbuf0 | [96K,128K) wbuf1. 1 sync per kc step.
__global__ __launch_bounds__(512, 2) void moe_gemm_k(
    const u16* __restrict__ tok, const u32* __restrict__ perm,
    const u32* __restrict__ tbl, const u32* __restrict__ meta,
    const u16* __restrict__ w1p, const u16* __restrict__ w2p,
    const float* __restrict__ b1, const float* __restrict__ b2,
    u16* __restrict__ eo) {
  __shared__ __attribute__((aligned(16))) unsigned char smem[131072];
  const int bid = blockIdx.x;
  if ((u32)bid >= meta[0]) return;
  const u32 ent = tbl[bid];
  const int e = (int)(ent & 15u);
  const int slot0 = (int)(ent >> 4);
  const int tid = threadIdx.x;
  const int lane = tid & 63;
  const int wv = tid >> 6;
  const int wr = (wv >> 2) * 64;
  const int wc = (wv & 3) * 64;
  const int fq = lane >> 4, fr = lane & 15;
  const u16* w1e = w1p + e * 65536;
  const u16* w2e = w2p + e * 65536;

  int woff[4];
#pragma unroll
  for (int it = 0; it < 4; ++it) {
    int s = tid + it * 512;
    int r = s >> 3;
    woff[it] = r * 256 + (((s & 7) ^ (r & 7)) << 3);
  }

  // prologue: gathered tok rows [128][256] + w1 kc0 -> wbuf0
#pragma unroll
  for (int it = 0; it < 8; ++it) {
    int s = tid + it * 512;
    int r = s >> 5, seg = s & 31;
    int cole = ((seg >> 3) << 6) + (((seg & 7) ^ (r & 7)) << 3);
    u32 rowtok = perm[slot0 + r];
    __builtin_amdgcn_global_load_lds(
        (const __attribute__((address_space(1))) u32*)(tok + (size_t)rowtok * 256 + cole),
        (__attribute__((address_space(3))) u32*)(smem + s * 16), 16, 0, 0);
  }
#pragma unroll
  for (int it = 0; it < 4; ++it)
    __builtin_amdgcn_global_load_lds(
        (const __attribute__((address_space(1))) u32*)(w1e + woff[it]),
        (__attribute__((address_space(3))) u32*)(smem + 65536 + (tid + it * 512) * 16),
        16, 0, 0);
  __syncthreads();

  // ---- GEMM1 (swapped): acc1[mc][nt] = w1-rows x tok-rows -> h^T frags ----
  f32x4 acc1[4][4];
#pragma unroll
  for (int mc = 0; mc < 4; ++mc)
#pragma unroll
    for (int nt = 0; nt < 4; ++nt) acc1[mc][nt] = (f32x4){0.f, 0.f, 0.f, 0.f};

#pragma unroll 1
  for (int kc = 0; kc < 4; ++kc) {
    const u16* nw = (kc < 3) ? (w1e + (kc + 1) * 64) : w2e;
    unsigned char* nb = smem + 65536 + (((kc + 1) & 1) * 32768);
#pragma unroll
    for (int it = 0; it < 4; ++it)
      __builtin_amdgcn_global_load_lds(
          (const __attribute__((address_space(1))) u32*)(nw + woff[it]),
          (__attribute__((address_space(3))) u32*)(nb + (tid + it * 512) * 16),
          16, 0, 0);
    const unsigned char* wb = smem + 65536 + ((kc & 1) * 32768);
#pragma unroll
    for (int khf = 0; khf < 2; ++khf) {
      short8 af1[4], bt[4];
#pragma unroll
      for (int mc = 0; mc < 4; ++mc) {
        int row = wc + mc * 16 + fr;
        int p = (khf * 4 + fq) ^ (row & 7);
        af1[mc] = *(const short8*)(wb + row * 128 + p * 16);
      }
#pragma unroll
      for (int nt = 0; nt < 4; ++nt) {
        int row = wr + nt * 16 + fr;
        int p = (khf * 4 + fq) ^ (row & 7);
        bt[nt] = *(const short8*)(smem + row * 512 + kc * 128 + p * 16);
      }
#pragma unroll
      for (int mc = 0; mc < 4; ++mc)
#pragma unroll
        for (int nt = 0; nt < 4; ++nt)
          acc1[mc][nt] = __builtin_amdgcn_mfma_f32_16x16x32_bf16(af1[mc], bt[nt], acc1[mc][nt], 0, 0, 0);
    }
    __syncthreads();
  }

  // epilogue: h = gelu(acc1 + b1[c]) -> Hs (aliases tok region; tok reads all done)
#pragma unroll
  for (int mc = 0; mc < 4; ++mc) {
    int k0 = wc + mc * 16 + fq * 4;
    float4 bv = *(const float4*)(b1 + e * 256 + k0);
#pragma unroll
    for (int nt = 0; nt < 4; ++nt) {
      int t = wr + nt * 16 + fr;
      u64 pk = 0;
#pragma unroll
      for (int j = 0; j < 4; ++j) {
        float v = acc1[mc][nt][j] + ((const float*)&bv)[j];
        float u = 1.5957691216057308f * (v + 0.044715f * v * v * v);
        float g = v / (1.0f + __expf(-u));
        pk |= (u64)f2bf(g) << (16 * j);
      }
      *(u64*)(smem + t * 512 + ((k0 * 2) ^ ((t & 7) << 4))) = pk;
    }
  }
  __syncthreads();  // Hs visible; wbuf0 already holds w2 kc0

  // ---- GEMM2: acc2[m][n] = h-rows x w2-rows ----
  f32x4 acc2[4][4];
#pragma unroll
  for (int m = 0; m < 4; ++m)
#pragma unroll
    for (int n = 0; n < 4; ++n) acc2[m][n] = (f32x4){0.f, 0.f, 0.f, 0.f};

#pragma unroll 1
  for (int kc = 0; kc < 4; ++kc) {
    if (kc < 3) {
      unsigned char* nb = smem + 65536 + (((kc + 1) & 1) * 32768);
      const u16* nw = w2e + (kc + 1) * 64;
#pragma unroll
      for (int it = 0; it < 4; ++it)
        __builtin_amdgcn_global_load_lds(
            (const __attribute__((address_space(1))) u32*)(nw + woff[it]),
            (__attribute__((address_space(3))) u32*)(nb + (tid + it * 512) * 16),
            16, 0, 0);
    }
    const unsigned char* wb = smem + 65536 + ((kc & 1) * 32768);
#pragma unroll
    for (int khf = 0; khf < 2; ++khf) {
      short8 af[4], bb[4];
#pragma unroll
      for (int m = 0; m < 4; ++m) {
        int row = wr + m * 16 + fr;
        int col = (kc * 128 + (khf * 4 + fq) * 16) ^ ((row & 7) << 4);
        af[m] = *(const short8*)(smem + row * 512 + col);
      }
#pragma unroll
      for (int n = 0; n < 4; ++n) {
        int row = wc + n * 16 + fr;
        int p = (khf * 4 + fq) ^ (row & 7);
        bb[n] = *(const short8*)(wb + row * 128 + p * 16);
      }
#pragma unroll
      for (int m = 0; m < 4; ++m)
#pragma unroll
        for (int n = 0; n < 4; ++n)
          acc2[m][n] = __builtin_amdgcn_mfma_f32_16x16x32_bf16(af[m], bb[n], acc2[m][n], 0, 0, 0);
    }
    __syncthreads();
  }

  float bs2[4];
#pragma unroll
  for (int n = 0; n < 4; ++n) bs2[n] = b2[e * 256 + wc + n * 16 + fr];
#pragma unroll
  for (int m = 0; m < 4; ++m)
#pragma unroll
    for (int j = 0; j < 4; ++j) {
      int rowslot = slot0 + wr + m * 16 + fq * 4 + j;
      u16* er = eo + (size_t)rowslot * 256 + wc;
#pragma unroll
      for (int n = 0; n < 4; ++n) er[n * 16 + fr] = f2bf(acc2[m][n][j] + bs2[n]);
    }
}

// ---------------- combine: xm = x(tok bf16) + g0*eo[p0] + g1*eo[p1] ------------------
// writes xmct (bf16 [C][T]) + pad (bf16 padded)
__global__ void combine_k(const u16* __restrict__ tok, const u16* __restrict__ eo,
                          const float* __restrict__ gw, const u32* __restrict__ tpos,
                          u16* __restrict__ xmct, u16* __restrict__ pad) {
  __shared__ float ld[64][65];
  __shared__ u32 pp[64][2];
  __shared__ float gg[64][2];
  int tt = blockIdx.x, cc = blockIdx.y, tid = threadIdx.x;
  if (tid < 128) {
    int tl = tid >> 1, s = tid & 1;
    int t = tt * 64 + tl;
    pp[tl][s] = tpos[t * 2 + s];
    gg[tl][s] = gw[t * 2 + s];
  }
  __syncthreads();
#pragma unroll
  for (int k = 0; k < 16; ++k) {
    int idx = tid + k * 256;
    int tl = idx >> 6, cl = idx & 63;
    int c = cc * 64 + cl;
    size_t o = (size_t)(tt * 64 + tl) * 256 + c;
    float e0 = bf2f(eo[(size_t)pp[tl][0] * 256 + c]);
    float e1 = bf2f(eo[(size_t)pp[tl][1] * 256 + c]);
    float v = bf2f(tok[o]) + gg[tl][0] * e0 + gg[tl][1] * e1;
    ld[tl][cl] = v;
    int t = tt * 64 + tl;
    int d = t >> 10, h = (t >> 5) & 31, w = t & 31;
    int prow = (d + 1) * 1156 + (h + 1) * 34 + (w + 1);
    pad[(size_t)prow * 256 + c] = f2bf(v);
  }
  __syncthreads();
#pragma unroll
  for (int k = 0; k < 16; ++k) {
    int idx = tid + k * 256;
    int cl = idx >> 6, tl = idx & 63;
    xmct[(size_t)(cc * 64 + cl) * 32768 + tt * 64 + tl] = f2bf(ld[tl][cl]);
  }
}

// ---------------- unified MFMA GEMM (convs + final 1x1), 2-phase double-buffer ------
// MODE 0: conv3x3x3 (XCD-swizzled ttile), y -> bf16 + fused BN partials
// MODE 3: final 1x1 conv, out[oc][t] = acc + bias + xmct_bf16[oc][t] (fp32 out)
template <int MODE>
__global__ __launch_bounds__(256, 2) void gemm_k(
    const u16* __restrict__ A, const u16* __restrict__ Bw,
    const float* __restrict__ bias, u16* __restrict__ yB,
    float* __restrict__ outF, const u16* __restrict__ xmct,
    float* __restrict__ part) {
  __shared__ __attribute__((aligned(16))) unsigned char smem[65536];
  const int tid = threadIdx.x;
  const int bx = blockIdx.x;
  const int ttile = (MODE == 0) ? ((bx & 7) * 32 + (bx >> 3)) : bx;  // XCD-bijective
  const int ctile = blockIdx.y;
  const int lane = tid & 63;
  const int wv = tid >> 6;
  const int wr = (wv >> 1) << 6;
  const int wc = (wv & 1) << 6;
  const int fq = lane >> 4;
  const int fr = lane & 15;

  int aoff[4], boff[4];
#pragma unroll
  for (int it = 0; it < 4; ++it) {
    int s = tid + it * 256;
    int r = s >> 3;
    int lsg = (s & 7) ^ (r & 7);
    if (MODE == 0) {
      int dd = ttile >> 3;
      int h0 = (ttile & 7) << 2;
      int base = dd * 1156 + (h0 + (r >> 5)) * 34 + (r & 31);
      aoff[it] = base * 256 + lsg * 8;
    } else {
      aoff[it] = (ttile * 128 + r) * 256 + lsg * 8;
    }
    boff[it] = (ctile * 128 + r) * 256 + lsg * 8;
  }

  f32x4 acc[4][4];
#pragma unroll
  for (int m = 0; m < 4; ++m)
#pragma unroll
    for (int n = 0; n < 4; ++n) acc[m][n] = (f32x4){0.f, 0.f, 0.f, 0.f};

  const int nStep = (MODE == 0) ? 108 : 4;  // step = tap*4 + kc

  auto stage = [&](int s, int buf) {
    int tap = (MODE == 0) ? (s >> 2) : 0;
    int kc = s & 3;
    int atap = 0, btap = 0;
    if (MODE == 0) {
      atap = ((tap / 9) * 1156 + ((tap / 3) % 3) * 34 + (tap % 3)) * 256;
      btap = tap * 65536;
    }
    const u16* Ak = A + atap + kc * 64;
    const u16* Bk = Bw + btap + kc * 64;
    unsigned char* sb = smem + buf * 32768;
#pragma unroll
    for (int it = 0; it < 4; ++it) {
      __builtin_amdgcn_global_load_lds(
          (const __attribute__((address_space(1))) u32*)(Ak + aoff[it]),
          (__attribute__((address_space(3))) u32*)(sb + (tid + it * 256) * 16),
          16, 0, 0);
      __builtin_amdgcn_global_load_lds(
          (const __attribute__((address_space(1))) u32*)(Bk + boff[it]),
          (__attribute__((address_space(3))) u32*)(sb + 16384 + (tid + it * 256) * 16),
          16, 0, 0);
    }
  };

  auto compute = [&](int buf) {
    const unsigned char* sb = smem + buf * 32768;
#pragma unroll
    for (int khf = 0; khf < 2; ++khf) {
      short8 af[4], bb[4];
#pragma unroll
      for (int m = 0; m < 4; ++m) {
        int row = wr + m * 16 + fr;
        int p = (khf * 4 + fq) ^ (row & 7);
        af[m] = *(const short8*)(sb + row * 128 + p * 16);
      }
#pragma unroll
      for (int n = 0; n < 4; ++n) {
        int row = wc + n * 16 + fr;
        int p = (khf * 4 + fq) ^ (row & 7);
        bb[n] = *(const short8*)(sb + 16384 + row * 128 + p * 16);
      }
#pragma unroll
      for (int m = 0; m < 4; ++m)
#pragma unroll
        for (int n = 0; n < 4; ++n)
          acc[m][n] = __builtin_amdgcn_mfma_f32_16x16x32_bf16(af[m], bb[n], acc[m][n], 0, 0, 0);
    }
  };

  stage(0, 0);
  asm volatile("s_waitcnt vmcnt(0)" ::: "memory");
  __builtin_amdgcn_s_barrier();
  int cur = 0;
#pragma unroll 1
  for (int s = 0; s < nStep; ++s) {
    if (s + 1 < nStep) stage(s + 1, cur ^ 1);
    compute(cur);
    asm volatile("s_waitcnt vmcnt(0)" ::: "memory");
    __builtin_amdgcn_s_barrier();
    cur ^= 1;
  }

  float bs[4];
#pragma unroll
  for (int n = 0; n < 4; ++n) bs[n] = bias[ctile * 128 + wc + n * 16 + fr];

  if (MODE == 3) {
#pragma unroll
    for (int m = 0; m < 4; ++m) {
      int trow = ttile * 128 + wr + m * 16 + fq * 4;
#pragma unroll
      for (int n = 0; n < 4; ++n) {
        int oc = ctile * 128 + wc + n * 16 + fr;
        size_t o = (size_t)oc * 32768 + trow;
        u64 xv = *(const u64*)(xmct + o);
        float4 w;
        w.x = acc[m][n][0] + bs[n] + bf2f((u32)(xv & 0xffffu));
        w.y = acc[m][n][1] + bs[n] + bf2f((u32)((xv >> 16) & 0xffffu));
        w.z = acc[m][n][2] + bs[n] + bf2f((u32)((xv >> 32) & 0xffffu));
        w.w = acc[m][n][3] + bs[n] + bf2f((u32)(xv >> 48));
        *(float4*)(outF + o) = w;
      }
    }
  } else {
    float sn[4] = {0, 0, 0, 0}, qn[4] = {0, 0, 0, 0};
#pragma unroll
    for (int m = 0; m < 4; ++m) {
#pragma unroll
      for (int j = 0; j < 4; ++j) {
        int t = ttile * 128 + wr + m * 16 + fq * 4 + j;
        u16* yr = yB + (size_t)t * 256 + ctile * 128 + wc;
#pragma unroll
        for (int n = 0; n < 4; ++n) {
          float v = acc[m][n][j] + bs[n];
          yr[n * 16 + fr] = f2bf(v);
          sn[n] += v;
          qn[n] += v * v;
        }
      }
    }
#pragma unroll
    for (int n = 0; n < 4; ++n) {
      float s = sn[n], q = qn[n];
      s += __shfl_xor(s, 16); s += __shfl_xor(s, 32);
      q += __shfl_xor(q, 16); q += __shfl_xor(q, 32);
      if (lane < 16) {
        int pi = (ttile * 2 + (wv >> 1)) * 256 + ctile * 128 + wc + n * 16 + fr;
        part[pi] = s;
        part[131072 + pi] = q;
      }
    }
  }
}

// ---------------- BN stats reduce: 16 blocks x 16 channels ----------------
__global__ void stats2_k(const float* __restrict__ part, const float* __restrict__ g,
                         const float* __restrict__ be, float* __restrict__ sf) {
  __shared__ float sred[16][16], qred[16][16];
  int tid = threadIdx.x;
  int cl = tid & 15, ch = tid >> 4;
  int c = blockIdx.x * 16 + cl;
  float s = 0, q = 0;
  for (int b = ch * 32; b < ch * 32 + 32; ++b) {
    s += part[b * 256 + c];
    q += part[131072 + b * 256 + c];
  }
  sred[ch][cl] = s;
  qred[ch][cl] = q;
  __syncthreads();
  if (ch == 0) {
    s = 0; q = 0;
#pragma unroll
    for (int k = 0; k < 16; ++k) { s += sred[k][cl]; q += qred[k][cl]; }
    float mean = s * (1.0f / 32768.0f);
    float var = q * (1.0f / 32768.0f) - mean * mean;
    float a = g[c] * rsqrtf(var + 1e-5f);
    sf[c] = a;
    sf[256 + c] = be[c] - mean * a;
  }
}

// ---------------- BN apply (+leaky, +skip); y bf16; skip from PADDED bf16 ----------
template <int V>
__global__ void bn_k(const u16* __restrict__ y, const float* __restrict__ sf,
                     const u16* __restrict__ skippad, u16* __restrict__ pad,
                     u16* __restrict__ bfo) {
  int gid = blockIdx.x * 256 + threadIdx.x;
  int t = gid >> 5, c0 = (gid & 31) << 3;
  size_t base = (size_t)t * 256 + c0;
  int d = t >> 10, h = (t >> 5) & 31, w = t & 31;
  int prow = (d + 1) * 1156 + (h + 1) * 34 + (w + 1);
  size_t pbase = (size_t)prow * 256 + c0;
  float v[8];
  uint4 yv = *(const uint4*)(y + base);
  v[0] = bf2f(yv.x & 0xffffu); v[1] = bf2f(yv.x >> 16);
  v[2] = bf2f(yv.y & 0xffffu); v[3] = bf2f(yv.y >> 16);
  v[4] = bf2f(yv.z & 0xffffu); v[5] = bf2f(yv.z >> 16);
  v[6] = bf2f(yv.w & 0xffffu); v[7] = bf2f(yv.w >> 16);
  const float4* ap = (const float4*)(sf + c0);
  float4 a0 = ap[0], a1 = ap[1];
  const float4* shp = (const float4*)(sf + 256 + c0);
  float4 s0 = shp[0], s1 = shp[1];
  v[0] = a0.x * v[0] + s0.x; v[1] = a0.y * v[1] + s0.y;
  v[2] = a0.z * v[2] + s0.z; v[3] = a0.w * v[3] + s0.w;
  v[4] = a1.x * v[4] + s1.x; v[5] = a1.y * v[5] + s1.y;
  v[6] = a1.z * v[6] + s1.z; v[7] = a1.w * v[7] + s1.w;
  if (V >= 1) {
    uint4 kv = *(const uint4*)(skippad + pbase);
    v[0] += bf2f(kv.x & 0xffffu); v[1] += bf2f(kv.x >> 16);
    v[2] += bf2f(kv.y & 0xffffu); v[3] += bf2f(kv.y >> 16);
    v[4] += bf2f(kv.z & 0xffffu); v[5] += bf2f(kv.z >> 16);
    v[6] += bf2f(kv.w & 0xffffu); v[7] += bf2f(kv.w >> 16);
  }
#pragma unroll
  for (int i = 0; i < 8; ++i) v[i] = v[i] > 0.0f ? v[i] : 0.01f * v[i];
  uint4 pk;
  pk.x = (u32)f2bf(v[0]) | ((u32)f2bf(v[1]) << 16);
  pk.y = (u32)f2bf(v[2]) | ((u32)f2bf(v[3]) << 16);
  pk.z = (u32)f2bf(v[4]) | ((u32)f2bf(v[5]) << 16);
  pk.w = (u32)f2bf(v[6]) | ((u32)f2bf(v[7]) << 16);
  if (V <= 1) *(uint4*)(pad + pbase) = pk;
  if (V == 2) *(uint4*)(bfo + base) = pk;
}

extern "C" void kernel_launch(void* const* d_in, const int* in_sizes, int n_in,
                              void* d_out, int out_size, void* d_ws, size_t ws_size,
                              hipStream_t stream) {
  (void)in_sizes; (void)n_in; (void)out_size; (void)ws_size;
  const float* x  = (const float*)d_in[0];
  const float* wg = (const float*)d_in[1];
  const float* w1 = (const float*)d_in[2];
  const float* b1 = (const float*)d_in[3];
  const float* w2 = (const float*)d_in[4];
  const float* b2 = (const float*)d_in[5];

  char* ws = (char*)d_ws;
  u16* tok    = (u16*)(ws + WS_TOK);
  u16* xmct   = (u16*)(ws + WS_XMCT);
  float* gw   = (float*)(ws + WS_GATES);
  u32* tpos   = (u32*)(ws + WS_GATES + 0x80000ull);
  u32* perm   = (u32*)(ws + WS_PERM);
  u32* tbl    = (u32*)(ws + WS_TBL);
  u32* meta   = (u32*)(ws + WS_META);
  u32* bcnt   = (u32*)(ws + WS_BCNT);
  u32* boff   = (u32*)(ws + WS_BOFF);
  u32* selb   = (u32*)(ws + WS_SEL);
  u16* P1     = (u16*)(ws + WS_P1);
  u16* P2     = (u16*)(ws + WS_P2);
  u16* ybuf   = (u16*)(ws + WS_Y);
  u16* eo     = (u16*)(ws + WS_Y);   // eo lives in Y before convs start
  u16* r2b    = (u16*)(ws + WS_R2);
  u16* wrb    = (u16*)(ws + WS_WRB);
  u16* w1p    = (u16*)(ws + WS_W1P);
  u16* w2p    = (u16*)(ws + WS_W2P);
  u16* c8p    = (u16*)(ws + WS_C8P);
  float* part = (float*)(ws + WS_PART);
  float* sf   = (float*)(ws + WS_SF);
  float* auxp = (float*)(ws + WS_AUXP);
  float* outp = (float*)d_out;

  halo_k<<<4913, 256, 0, stream>>>(P1, P2);
  gate_k<<<128, 256, 0, stream>>>(x, wg, gw, selb, bcnt, auxp);
  trans_in_k<<<dim3(512, 4), 256, 0, stream>>>(x, tok);
  pack_rb_k<<<1024, 256, 0, stream>>>((const float*)d_in[6], (const float*)d_in[10],
                                      (const float*)d_in[14], (const float*)d_in[18], wrb);
  pack_tr_k<<<dim3(16, 16), 256, 0, stream>>>(w1, w2, w1p, w2p);
  cvt_k<<<256, 256, 0, stream>>>((const float*)d_in[22], c8p, 65536);

  scan_k<<<1, 256, 0, stream>>>(bcnt, boff, tbl, meta, perm);
  scatter_k<<<128, 256, 0, stream>>>(selb, boff, perm, tpos);
  moe_gemm_k<<<520, 512, 0, stream>>>(tok, perm, tbl, meta, w1p, w2p, b1, b2, eo);
  combine_k<<<dim3(512, 4), 256, 0, stream>>>(tok, eo, gw, tpos, xmct, P1);

  // resblock 1 (P1 holds xm padded; skip chain lives in P1 as bf16)
  gemm_k<0><<<dim3(256, 2), 256, 0, stream>>>(P1, wrb + 0 * 1769472, (const float*)d_in[7],
                                              ybuf, nullptr, nullptr, part);
  stats2_k<<<16, 256, 0, stream>>>(part, (const float*)d_in[8], (const float*)d_in[9], sf);
  bn_k<0><<<4096, 256, 0, stream>>>(ybuf, sf, nullptr, P2, nullptr);
  gemm_k<0><<<dim3(256, 2), 256, 0, stream>>>(P2, wrb + 1 * 1769472, (const float*)d_in[11],
                                              ybuf, nullptr, nullptr, part);
  stats2_k<<<16, 256, 0, stream>>>(part, (const float*)d_in[12], (const float*)d_in[13], sf);
  bn_k<1><<<4096, 256, 0, stream>>>(ybuf, sf, P1, P1, nullptr);  // r1 = bn+xm(P1) -> P1

  // resblock 2 (P1 holds r1 padded)
  gemm_k<0><<<dim3(256, 2), 256, 0, stream>>>(P1, wrb + 2 * 1769472, (const float*)d_in[15],
                                              ybuf, nullptr, nullptr, part);
  stats2_k<<<16, 256, 0, stream>>>(part, (const float*)d_in[16], (const float*)d_in[17], sf);
  bn_k<0><<<4096, 256, 0, stream>>>(ybuf, sf, nullptr, P2, nullptr);
  gemm_k<0><<<dim3(256, 2), 256, 0, stream>>>(P2, wrb + 3 * 1769472, (const float*)d_in[19],
                                              ybuf, nullptr, nullptr, part);
  stats2_k<<<16, 256, 0, stream>>>(part, (const float*)d_in[20], (const float*)d_in[21], sf);
  bn_k<2><<<4096, 256, 0, stream>>>(ybuf, sf, P1, nullptr, r2b);  // r2 = bn+r1(P1) -> flat

  // final: out = xm + conv1x1(res)
  gemm_k<3><<<dim3(256, 2), 256, 0, stream>>>(r2b, c8p, (const float*)d_in[23], nullptr,
                                              outp, xmct, nullptr);
  aux_k<<<1, 64, 0, stream>>>(auxp, outp + 8388608);
}